// Round 3
// baseline (1024.879 us; speedup 1.0000x reference)
//
#include <hip/hip_runtime.h>
#include <math.h>

// Model dims: S=87, B=8, D=5, T=30, H=64, G=192, K_text=512

typedef short s16x8 __attribute__((ext_vector_type(8)));
typedef float f32x4 __attribute__((ext_vector_type(4)));

__device__ __forceinline__ float sigmoidf_(float x){ return 1.0f/(1.0f+expf(-x)); }

__device__ __forceinline__ float warp_sum(float v){
  #pragma unroll
  for (int off=32; off>0; off>>=1) v += __shfl_xor(v, off, 64);
  return v;
}
__device__ __forceinline__ float warp_max(float v){
  #pragma unroll
  for (int off=32; off>0; off>>=1) v = fmaxf(v, __shfl_xor(v, off, 64));
  return v;
}

__device__ __forceinline__ float readlane_f(float x, int k){
  return __int_as_float(__builtin_amdgcn_readlane(__float_as_int(x), k));
}

// truncation split: x ~= hi + lo with |err| ~ 2^-14 |x| (3 VALU ops/elem)
__device__ __forceinline__ void split_bf16(float x, unsigned short& hi, unsigned short& lo){
  unsigned u = __float_as_uint(x);
  hi = (unsigned short)(u >> 16);
  float r = x - __uint_as_float(u & 0xffff0000u);
  lo = (unsigned short)(__float_as_uint(r) >> 16);
}

union U8 { unsigned short u[8]; s16x8 v; };

// ---------------------------------------------------------------------------
// Kernel 1: tweet input projection via split-bf16 MFMA.
// 2-deep register ping-pong prefetch: chunk kc+2 loads issue during chunk kc's
// MFMA phase -> ~2 phases of HBM latency cover.
// ---------------------------------------------------------------------------
__global__ __launch_bounds__(256) void k_tweet_proj(
    const float* __restrict__ text, const float* __restrict__ Wih,
    const float* __restrict__ bih, float* __restrict__ xi_t){
  __shared__ short lds[17408];   // Ah[2560] Al[2560] Bh[6144] Bl[6144] shorts = 34816 B
  const int tid = threadIdx.x;
  const int mb = blockIdx.x, d = blockIdx.y, s = blockIdx.z;
  const int lane = tid & 63, w = tid >> 6, quad = lane >> 4;

  const float* srcp[5]; int dsth[5]; int dstl[5]; bool val[5];
  #pragma unroll
  for (int i=0;i<5;++i){
    int c = tid + i*256;
    val[i] = (c < 1088);
    int cc = val[i] ? c : 0;
    int tile = cc>>6, slot = cc&63, k8 = slot>>4, i16 = slot&15;
    if (tile < 5){
      int row = mb*80 + tile*16 + i16;           // always < 240
      int b = row/30, t = row - b*30;
      srcp[i] = text + (size_t)(b*13050 + s*150 + d*30 + t)*512 + k8*8;
      dsth[i] = tile*512 + slot*8;
      dstl[i] = dsth[i] + 2560;
    } else {
      int g = (tile-5)*16 + i16;
      srcp[i] = Wih + (size_t)(s*192+g)*512 + k8*8;
      dsth[i] = 5120 + (tile-5)*512 + slot*8;
      dstl[i] = dsth[i] + 6144;
    }
  }

  f32x4 acc[5][3] = {};

  // prologue: preload chunks 0 (A regs) and 1 (B regs)
  float4 v0a[5], v1a[5], v0b[5], v1b[5];
  #pragma unroll
  for (int i=0;i<5;++i){
    if (val[i]){
      v0a[i] = *(const float4*)srcp[i];
      v1a[i] = *(const float4*)(srcp[i]+4);
      v0b[i] = *(const float4*)(srcp[i]+32);
      v1b[i] = *(const float4*)(srcp[i]+36);
    }
  }

  for (int kc=0; kc<16; kc+=2){
    // ---- even chunk (A regs) ----
    __syncthreads();
    #pragma unroll
    for (int i=0;i<5;++i){
      if (val[i]){
        float xs[8] = {v0a[i].x,v0a[i].y,v0a[i].z,v0a[i].w,v1a[i].x,v1a[i].y,v1a[i].z,v1a[i].w};
        if (kc+2 < 16){
          const float* sp = srcp[i] + (kc+2)*32;
          v0a[i] = *(const float4*)sp;
          v1a[i] = *(const float4*)(sp+4);
        }
        U8 hv, lv;
        #pragma unroll
        for (int j=0;j<8;++j) split_bf16(xs[j], hv.u[j], lv.u[j]);
        *(s16x8*)&lds[dsth[i]] = hv.v;
        *(s16x8*)&lds[dstl[i]] = lv.v;
      }
    }
    __syncthreads();
    {
      s16x8 ah[5], al[5], bh[3], bl[3];
      #pragma unroll
      for (int mt=0;mt<5;++mt){
        ah[mt] = *(const s16x8*)&lds[mt*512 + lane*8];
        al[mt] = *(const s16x8*)&lds[2560 + mt*512 + lane*8];
      }
      #pragma unroll
      for (int nl=0;nl<3;++nl){
        int nt = w*3+nl;
        bh[nl] = *(const s16x8*)&lds[5120 + nt*512 + lane*8];
        bl[nl] = *(const s16x8*)&lds[11264 + nt*512 + lane*8];
      }
      #pragma unroll
      for (int mt=0;mt<5;++mt){
        #pragma unroll
        for (int nl=0;nl<3;++nl){
          acc[mt][nl] = __builtin_amdgcn_mfma_f32_16x16x32_bf16(ah[mt], bh[nl], acc[mt][nl], 0,0,0);
          acc[mt][nl] = __builtin_amdgcn_mfma_f32_16x16x32_bf16(ah[mt], bl[nl], acc[mt][nl], 0,0,0);
          acc[mt][nl] = __builtin_amdgcn_mfma_f32_16x16x32_bf16(al[mt], bh[nl], acc[mt][nl], 0,0,0);
        }
      }
    }
    // ---- odd chunk (B regs) ----
    __syncthreads();
    #pragma unroll
    for (int i=0;i<5;++i){
      if (val[i]){
        float xs[8] = {v0b[i].x,v0b[i].y,v0b[i].z,v0b[i].w,v1b[i].x,v1b[i].y,v1b[i].z,v1b[i].w};
        if (kc+3 < 16){
          const float* sp = srcp[i] + (kc+3)*32;
          v0b[i] = *(const float4*)sp;
          v1b[i] = *(const float4*)(sp+4);
        }
        U8 hv, lv;
        #pragma unroll
        for (int j=0;j<8;++j) split_bf16(xs[j], hv.u[j], lv.u[j]);
        *(s16x8*)&lds[dsth[i]] = hv.v;
        *(s16x8*)&lds[dstl[i]] = lv.v;
      }
    }
    __syncthreads();
    {
      s16x8 ah[5], al[5], bh[3], bl[3];
      #pragma unroll
      for (int mt=0;mt<5;++mt){
        ah[mt] = *(const s16x8*)&lds[mt*512 + lane*8];
        al[mt] = *(const s16x8*)&lds[2560 + mt*512 + lane*8];
      }
      #pragma unroll
      for (int nl=0;nl<3;++nl){
        int nt = w*3+nl;
        bh[nl] = *(const s16x8*)&lds[5120 + nt*512 + lane*8];
        bl[nl] = *(const s16x8*)&lds[11264 + nt*512 + lane*8];
      }
      #pragma unroll
      for (int mt=0;mt<5;++mt){
        #pragma unroll
        for (int nl=0;nl<3;++nl){
          acc[mt][nl] = __builtin_amdgcn_mfma_f32_16x16x32_bf16(ah[mt], bh[nl], acc[mt][nl], 0,0,0);
          acc[mt][nl] = __builtin_amdgcn_mfma_f32_16x16x32_bf16(ah[mt], bl[nl], acc[mt][nl], 0,0,0);
          acc[mt][nl] = __builtin_amdgcn_mfma_f32_16x16x32_bf16(al[mt], bh[nl], acc[mt][nl], 0,0,0);
        }
      }
    }
  }

  // epilogue: C/D layout col=lane&15, row=quad*4+reg
  const size_t obase = (size_t)(s*5+d)*240;
  #pragma unroll
  for (int nl=0;nl<3;++nl){
    int g = (w*3+nl)*16 + (lane&15);
    float bias = bih[s*192+g];
    #pragma unroll
    for (int mt=0;mt<5;++mt){
      #pragma unroll
      for (int reg=0;reg<4;++reg){
        int row = mb*80 + mt*16 + quad*4 + reg;
        xi_t[(obase+row)*192 + g] = acc[mt][nl][reg] + bias;
      }
    }
  }
}

// ---------------------------------------------------------------------------
// Kernel 2: tweet GRU (30 steps), one block per (s,d).
// REWRITE: weights register-resident (t-invariant; old version re-read them
// from LDS every step -> LDS-pipe-bound at 480 b128/block-step = 11.5K cy).
// Thread (g 0..191, bh 0..1): holds Whh[g][0..63] in 64 VGPRs, computes gate
// pre-activations for b = bh*4..bh*4+3 via v_readlane h-broadcast (no LDS).
// ---------------------------------------------------------------------------
__global__ __launch_bounds__(384) void k_gru30(
    const float* __restrict__ xi_t, const float* __restrict__ Whh, const float* __restrict__ bhh,
    const float* __restrict__ W1, const float* __restrict__ b1,
    float* __restrict__ full_t, float* __restrict__ q){
  __shared__ float gh[1536];   // [b][192]
  __shared__ float h[544];     // [b][68]
  const int tid = threadIdx.x;
  const int bid = blockIdx.x;
  const int s = bid/5;
  const int lane = tid & 63;
  const int bh = tid / 192;        // 0 or 1
  const int g  = tid - bh*192;     // 0..191 (== lane-consecutive within a wave)

  // weight registers: wv[kq] = Whh[s*192+g][kq*4 .. kq*4+3]
  float4 wv[16];
  {
    const float* wr = Whh + (size_t)(s*192+g)*64;
    #pragma unroll
    for (int kq=0;kq<16;++kq) wv[kq] = *(const float4*)(wr + kq*4);
  }
  const float bhhg = bhh[s*192+g];

  for (int idx=tid; idx<544; idx+=384) h[idx] = 0.f;

  const size_t sd240 = (size_t)bid*240;
  // apply-phase ownership: item idx=tid (if<512) and idx=tid+384 (tid<128)
  float xp[2][3]; float hprev[2] = {0.f, 0.f};
  #pragma unroll
  for (int u2=0;u2<2;++u2){
    int idx = tid + u2*384;
    if (idx < 512){
      int bb = idx>>6, j = idx&63;
      const float* xr = xi_t + (sd240 + bb*30 + 0)*192 + j;
      xp[u2][0]=xr[0]; xp[u2][1]=xr[64]; xp[u2][2]=xr[128];
    }
  }
  __syncthreads();

  float hreg[4] = {0.f,0.f,0.f,0.f};   // hreg[i] = h[bh*4+i][lane]

  for (int t=0; t<30; ++t){
    // ---- gate GEMV, all from registers ----
    float a0=bhhg, a1=bhhg, a2=bhhg, a3=bhhg;
    #pragma unroll
    for (int kq=0;kq<16;++kq){
      const float4 w4 = wv[kq];
      #pragma unroll
      for (int r=0;r<4;++r){
        const int k = kq*4 + r;
        const float wk = (r==0)?w4.x:(r==1)?w4.y:(r==2)?w4.z:w4.w;
        a0 = fmaf(readlane_f(hreg[0], k), wk, a0);
        a1 = fmaf(readlane_f(hreg[1], k), wk, a1);
        a2 = fmaf(readlane_f(hreg[2], k), wk, a2);
        a3 = fmaf(readlane_f(hreg[3], k), wk, a3);
      }
    }
    gh[(bh*4+0)*192 + g] = a0;
    gh[(bh*4+1)*192 + g] = a1;
    gh[(bh*4+2)*192 + g] = a2;
    gh[(bh*4+3)*192 + g] = a3;
    __syncthreads();

    // ---- gate apply ----
    float cur[2][3];
    #pragma unroll
    for (int u2=0;u2<2;++u2){ cur[u2][0]=xp[u2][0]; cur[u2][1]=xp[u2][1]; cur[u2][2]=xp[u2][2]; }
    if (t < 29){
      #pragma unroll
      for (int u2=0;u2<2;++u2){
        int idx = tid + u2*384;
        if (idx < 512){
          int bb = idx>>6, j = idx&63;
          const float* xr = xi_t + (sd240 + bb*30 + t + 1)*192 + j;
          xp[u2][0]=xr[0]; xp[u2][1]=xr[64]; xp[u2][2]=xr[128];
        }
      }
    }
    #pragma unroll
    for (int u2=0;u2<2;++u2){
      int idx = tid + u2*384;
      if (idx < 512){
        int bb = idx>>6, j = idx&63;
        float r = sigmoidf_(cur[u2][0] + gh[bb*192+j]);
        float z = sigmoidf_(cur[u2][1] + gh[bb*192+64+j]);
        float n = tanhf(   cur[u2][2] + r*gh[bb*192+128+j]);
        float hn = (1.f - z)*n + z*hprev[u2];
        hprev[u2] = hn;
        h[bb*68+j] = hn;
        full_t[(sd240 + bb*30 + t)*64 + j] = hn;
      }
    }
    __syncthreads();
    // reload h broadcast registers for next step's GEMV
    hreg[0] = h[(bh*4+0)*68 + lane];
    hreg[1] = h[(bh*4+1)*68 + lane];
    hreg[2] = h[(bh*4+2)*68 + lane];
    hreg[3] = h[(bh*4+3)*68 + lane];
  }

  // q = W1 h_last + b1
  for (int idx=tid; idx<512; idx+=384){
    int bb = idx>>6, j = idx&63;
    float acc = b1[s*64+j];
    const float* wr = W1 + (size_t)(s*64+j)*64;
    #pragma unroll
    for (int kq=0;kq<16;++kq){
      float4 w4 = *(const float4*)(wr+kq*4);
      acc += h[bb*68+kq*4+0]*w4.x + h[bb*68+kq*4+1]*w4.y
           + h[bb*68+kq*4+2]*w4.z + h[bb*68+kq*4+3]*w4.w;
    }
    q[(size_t)bid*512 + idx] = acc;
  }
}

// ---------------------------------------------------------------------------
// Kernel 3: attention projection u = full_t @ W2^T via split-bf16 MFMA, fused
// with score=V.tanh(q+u+b2)+bV, softmax over T, weighted sum -> news.
// ---------------------------------------------------------------------------
__global__ __launch_bounds__(256) void k_uproj(
    const float* __restrict__ full_t, const float* __restrict__ q,
    const float* __restrict__ W2, const float* __restrict__ b2,
    const float* __restrict__ V, const float* __restrict__ bV,
    float* __restrict__ news){
  __shared__ short lds[19456];   // Ah[7680] Al[7680] Bh[2048] Bl[2048] = 38912 B
  float* scpart = (float*)&lds[15360];
  float* ssc = scpart + 960;
  float* swt = ssc + 240;
  const int tid = threadIdx.x, lane = tid&63, w = tid>>6, quad = lane>>4;
  const int bid = blockIdx.x;
  const int s = bid/5;
  const size_t sd240 = (size_t)bid*240;

  const float* srcp2[5]; int dh2[5]; int ldo2[5]; bool val2[5];
  #pragma unroll
  for (int i=0;i<5;++i){
    int idx = tid + i*256;
    val2[i] = (idx < 1216);
    int ix = val2[i] ? idx : 0;
    if (ix < 960){
      int r = ix>>2, kc8 = ix&3;
      srcp2[i] = full_t + (sd240 + r)*64 + kc8*8;
      dh2[i] = ((r>>4)*64 + ((r&15)|(kc8<<4)))*8; ldo2[i] = 7680;
    } else {
      int c = ix - 960; int j = c>>2, kc8 = c&3;
      srcp2[i] = W2 + (size_t)(s*64+j)*64 + kc8*8;
      dh2[i] = 15360 + ((j>>4)*64 + ((j&15)|(kc8<<4)))*8; ldo2[i] = 2048;
    }
  }

  float4 w0r[5], w1r[5];
  #pragma unroll
  for (int i=0;i<5;++i){
    if (val2[i]){
      w0r[i] = *(const float4*)srcp2[i];
      w1r[i] = *(const float4*)(srcp2[i]+4);
    }
  }

  f32x4 acc[15] = {};
  for (int kc=0; kc<2; ++kc){
    __syncthreads();
    #pragma unroll
    for (int i=0;i<5;++i){
      if (val2[i]){
        float xs[8] = {w0r[i].x,w0r[i].y,w0r[i].z,w0r[i].w,w1r[i].x,w1r[i].y,w1r[i].z,w1r[i].w};
        U8 hv, lv;
        #pragma unroll
        for (int j2=0;j2<8;++j2) split_bf16(xs[j2], hv.u[j2], lv.u[j2]);
        *(s16x8*)&lds[dh2[i]] = hv.v;
        *(s16x8*)&lds[dh2[i]+ldo2[i]] = lv.v;
        if (kc == 0){
          const float* sp = srcp2[i] + 32;
          w0r[i] = *(const float4*)sp;
          w1r[i] = *(const float4*)(sp+4);
        }
      }
    }
    __syncthreads();
    s16x8 bh = *(const s16x8*)&lds[15360 + (w*64+lane)*8];
    s16x8 bl = *(const s16x8*)&lds[17408 + (w*64+lane)*8];
    #pragma unroll
    for (int mt=0;mt<15;++mt){
      s16x8 ah = *(const s16x8*)&lds[(mt*64+lane)*8];
      s16x8 al = *(const s16x8*)&lds[7680+(mt*64+lane)*8];
      acc[mt] = __builtin_amdgcn_mfma_f32_16x16x32_bf16(ah, bh, acc[mt], 0,0,0);
      acc[mt] = __builtin_amdgcn_mfma_f32_16x16x32_bf16(ah, bl, acc[mt], 0,0,0);
      acc[mt] = __builtin_amdgcn_mfma_f32_16x16x32_bf16(al, bh, acc[mt], 0,0,0);
    }
  }
  __syncthreads();

  {
    int j = w*16 + (lane&15);
    float Vj = V[s*64+j], b2j = b2[s*64+j];
    const float* qb = q + (size_t)bid*512;
    #pragma unroll
    for (int mt=0;mt<15;++mt){
      #pragma unroll
      for (int reg=0;reg<4;++reg){
        int row = mt*16 + quad*4 + reg;
        int bb = row/30;
        float val = tanhf(acc[mt][reg] + b2j + qb[bb*64+j]) * Vj;
        val += __shfl_xor(val, 1, 64);
        val += __shfl_xor(val, 2, 64);
        val += __shfl_xor(val, 4, 64);
        val += __shfl_xor(val, 8, 64);
        if ((lane&15)==0) scpart[w*240 + row] = val;
      }
    }
  }
  __syncthreads();
  float bVs = bV[s];
  for (int idx=tid; idx<240; idx+=256)
    ssc[idx] = scpart[idx] + scpart[240+idx] + scpart[480+idx] + scpart[720+idx] + bVs;
  __syncthreads();
  if (tid < 8){
    float mx = -1e30f;
    for (int t=0;t<30;++t) mx = fmaxf(mx, ssc[tid*30+t]);
    float ssum = 0.f;
    for (int t=0;t<30;++t){ float e = expf(ssc[tid*30+t]-mx); swt[tid*30+t] = e; ssum += e; }
    float inv = 1.f/ssum;
    for (int t=0;t<30;++t) swt[tid*30+t] *= inv;
  }
  __syncthreads();
  for (int idx=tid; idx<512; idx+=256){
    int bb = idx>>6, jj = idx&63;
    float a = 0.f;
    for (int t=0;t<30;++t) a += swt[bb*30+t]*full_t[(sd240 + bb*30 + t)*64 + jj];
    news[(size_t)bid*512 + idx] = a;
  }
}

// ---------------------------------------------------------------------------
// Fused stock kernel: replaces k_price (blocks 0..86) and k_day (87..173).
// ---------------------------------------------------------------------------
__global__ __launch_bounds__(384) void k_stock(
    const float* __restrict__ price, const float* __restrict__ news,
    const float* __restrict__ pWih, const float* __restrict__ pWhh,
    const float* __restrict__ pbih, const float* __restrict__ pbhh,
    const float* __restrict__ pW1, const float* __restrict__ pb1,
    const float* __restrict__ pW2, const float* __restrict__ pb2,
    const float* __restrict__ pV, const float* __restrict__ pbV,
    const float* __restrict__ dWih, const float* __restrict__ dWhh,
    const float* __restrict__ dbih, const float* __restrict__ dbhh,
    const float* __restrict__ dW1, const float* __restrict__ db1,
    const float* __restrict__ dW2, const float* __restrict__ db2,
    const float* __restrict__ dV, const float* __restrict__ dbV,
    float* __restrict__ x_price, float* __restrict__ text_vec){
  __shared__ float sm[27904];          // 111.6 KB
  float* Wt  = sm;            // 12288: transposed Wih, then Whh, then W2t reuse
  float* xi  = sm + 12288;    // 7680
  float* full= sm + 19968;    // 2560
  float* h   = sm + 22528;    // 544 (8 x 68)
  float* gh  = sm + 23072;    // 1568 (8 x 196); tail reuse: Vs/b2s/sc/wsm
  float* nw  = sm + 24640;    // 2560
  float* bihs= sm + 27200;    // 192
  float* qq  = sm + 27392;    // 512

  const int tid = threadIdx.x;
  const int bid = blockIdx.x;
  const bool isday = (bid >= 87);
  const int s = isday ? (bid - 87) : bid;

  const float* Wih = isday ? dWih : pWih;
  const float* Whh = isday ? dWhh : pWhh;
  const float* bih = isday ? dbih : pbih;
  const float* bhh = isday ? dbhh : pbhh;
  const float* W1  = isday ? dW1  : pW1;
  const float* b1  = isday ? db1  : pb1;
  const float* W2  = isday ? dW2  : pW2;
  const float* b2  = isday ? db2  : pb2;
  const float* V   = isday ? dV   : pV;
  const float* bV  = isday ? dbV  : pbV;

  // ---- phase A: stage inputs, zero h, stage bih, stage Wih (transposed) ----
  if (isday){
    for (int idx=tid; idx<2560; idx+=384) nw[idx] = news[(size_t)s*2560 + idx];
    for (int idx=tid; idx<3072; idx+=384){
      int g = idx>>4, kq = idx&15;
      float4 wv = *(const float4*)&Wih[(size_t)(s*192+g)*64 + kq*4];
      Wt[(kq*4+0)*192+g]=wv.x; Wt[(kq*4+1)*192+g]=wv.y;
      Wt[(kq*4+2)*192+g]=wv.z; Wt[(kq*4+3)*192+g]=wv.w;
    }
  } else {
    for (int idx=tid; idx<120; idx+=384){
      int bb = idx/15, rem = idx - bb*15; int dd = rem/3, k = rem - dd*3;
      nw[idx] = price[(size_t)((bb*87+s)*5+dd)*3 + k];
    }
    for (int idx=tid; idx<576; idx+=384) Wt[idx] = Wih[(size_t)s*576 + idx]; // [g][3]
  }
  for (int idx=tid; idx<544; idx+=384) h[idx] = 0.f;
  for (int idx=tid; idx<192; idx+=384) bihs[idx] = bih[s*192+idx];
  __syncthreads();

  // ---- phase B: xi[bd*192+g] from LDS only ----
  if (isday){
    for (int idx=tid; idx<7680; idx+=384){
      int bd = idx/192, g = idx - bd*192;
      int bb = bd/5, dd = bd - bb*5;
      const float* xr = nw + (dd*8+bb)*64;
      float a0=0.f,a1=0.f,a2=0.f,a3=0.f;
      #pragma unroll
      for (int k=0;k<64;k+=4){
        a0 += xr[k]  *Wt[(k  )*192+g];
        a1 += xr[k+1]*Wt[(k+1)*192+g];
        a2 += xr[k+2]*Wt[(k+2)*192+g];
        a3 += xr[k+3]*Wt[(k+3)*192+g];
      }
      xi[idx] = bihs[g] + ((a0+a1)+(a2+a3));
    }
  } else {
    for (int idx=tid; idx<7680; idx+=384){
      int bd = idx/192, g = idx - bd*192;
      xi[idx] = bihs[g] + nw[bd*3]*Wt[g*3] + nw[bd*3+1]*Wt[g*3+1] + nw[bd*3+2]*Wt[g*3+2];
    }
  }
  __syncthreads();

  // ---- phase C: stage Whh transposed (overwrite Wt) ----
  for (int idx=tid; idx<3072; idx+=384){
    int g = idx>>4, kq = idx&15;
    float4 wv = *(const float4*)&Whh[(size_t)(s*192+g)*64 + kq*4];
    Wt[(kq*4+0)*192+g]=wv.x; Wt[(kq*4+1)*192+g]=wv.y;
    Wt[(kq*4+2)*192+g]=wv.z; Wt[(kq*4+3)*192+g]=wv.w;
  }
  const int gq = tid>>3, b = tid&7;        // gq 0..47, b 0..7
  float4 bh4 = *(const float4*)&bhh[s*192 + gq*4];
  __syncthreads();

  // ---- phase D: 5 GRU steps ----
  for (int dd=0; dd<5; ++dd){
    float4 acc = bh4;
    #pragma unroll
    for (int kq=0;kq<16;++kq){
      float4 h4 = *(const float4*)&h[b*68+kq*4];
      float4 w0 = *(const float4*)&Wt[(kq*4+0)*192+gq*4];
      float4 w1 = *(const float4*)&Wt[(kq*4+1)*192+gq*4];
      float4 w2 = *(const float4*)&Wt[(kq*4+2)*192+gq*4];
      float4 w3 = *(const float4*)&Wt[(kq*4+3)*192+gq*4];
      acc.x += h4.x*w0.x + h4.y*w1.x + h4.z*w2.x + h4.w*w3.x;
      acc.y += h4.x*w0.y + h4.y*w1.y + h4.z*w2.y + h4.w*w3.y;
      acc.z += h4.x*w0.z + h4.y*w1.z + h4.z*w2.z + h4.w*w3.z;
      acc.w += h4.x*w0.w + h4.y*w1.w + h4.z*w2.w + h4.w*w3.w;
    }
    *(float4*)&gh[b*196+gq*4] = acc;
    __syncthreads();
    for (int idx=tid; idx<512; idx+=384){
      int bb = idx>>6, j = idx&63;
      const float* xr = xi + (bb*5+dd)*192;
      float r = sigmoidf_(xr[j]     + gh[bb*196+j]);
      float z = sigmoidf_(xr[64+j]  + gh[bb*196+64+j]);
      float n = tanhf(   xr[128+j] + r*gh[bb*196+128+j]);
      float hv = h[bb*68+j];
      float hn = (1.f-z)*n + z*hv;
      h[bb*68+j] = hn;
      full[(bb*5+dd)*64 + j] = hn;
    }
    __syncthreads();
  }

  // ---- phase E: Bahdanau attention over D=5 ----
  float* W2t = Wt;                 // 4096, gates done
  float* Vs  = gh;                 // 64
  float* b2s = gh + 64;            // 64
  float* sc  = gh + 128;           // 40
  float* wsm = gh + 168;           // 40
  for (int idx=tid; idx<512; idx+=384){
    int bb = idx>>6, j = idx&63;
    float a0=0.f,a1=0.f,a2=0.f,a3=0.f;
    float accq = b1[s*64+j];
    const float* wr = W1 + (size_t)(s*64+j)*64;
    #pragma unroll
    for (int kq=0;kq<16;++kq){
      float4 w4 = *(const float4*)(wr+kq*4);
      a0 += h[bb*68+kq*4+0]*w4.x; a1 += h[bb*68+kq*4+1]*w4.y;
      a2 += h[bb*68+kq*4+2]*w4.z; a3 += h[bb*68+kq*4+3]*w4.w;
    }
    qq[idx] = accq + ((a0+a1)+(a2+a3));
  }
  for (int idx=tid; idx<1024; idx+=384){
    int j = idx>>4, kq = idx&15;
    float4 w4 = *(const float4*)&W2[(size_t)(s*64+j)*64 + kq*4];
    W2t[(kq*4+0)*64+j]=w4.x; W2t[(kq*4+1)*64+j]=w4.y;
    W2t[(kq*4+2)*64+j]=w4.z; W2t[(kq*4+3)*64+j]=w4.w;
  }
  for (int idx=tid; idx<64; idx+=384){ Vs[idx]=V[s*64+idx]; b2s[idx]=b2[s*64+idx]; }
  __syncthreads();
  const int w = tid>>6, lane = tid&63;
  const float bVs = bV[s];
  for (int pair=w; pair<40; pair+=6){
    int bb = pair/5, dd = pair - bb*5;
    const float* fr = full + (bb*5+dd)*64;
    float u0=0.f,u1=0.f,u2=0.f,u3=0.f;
    #pragma unroll
    for (int k=0;k<64;k+=4){
      u0 += W2t[(k  )*64+lane]*fr[k];
      u1 += W2t[(k+1)*64+lane]*fr[k+1];
      u2 += W2t[(k+2)*64+lane]*fr[k+2];
      u3 += W2t[(k+3)*64+lane]*fr[k+3];
    }
    float u = qq[bb*64+lane] + b2s[lane] + ((u0+u1)+(u2+u3));
    float p = warp_sum(tanhf(u)*Vs[lane]);
    if (lane==0) sc[pair] = p + bVs;
  }
  __syncthreads();
  if (tid<8){
    float mx=-1e30f; for (int dd=0;dd<5;++dd) mx=fmaxf(mx, sc[tid*5+dd]);
    float ssum=0.f;
    for (int dd=0;dd<5;++dd){ float e=expf(sc[tid*5+dd]-mx); wsm[tid*5+dd]=e; ssum+=e; }
    float inv=1.f/ssum;
    for (int dd=0;dd<5;++dd) wsm[tid*5+dd]*=inv;
  }
  __syncthreads();
  float* outv = isday ? text_vec : x_price;
  for (int idx=tid; idx<512; idx+=384){
    int bb=idx>>6, j=idx&63;
    float acc=0.f;
    for (int dd=0;dd<5;++dd) acc += wsm[bb*5+dd]*full[(bb*5+dd)*64+j];
    outv[(size_t)(s*8+bb)*64 + j] = acc;
  }
}

// ---------------------------------------------------------------------------
__global__ __launch_bounds__(256) void k_bilinear(
    const float* __restrict__ text_vec, const float* __restrict__ x_price,
    const float* __restrict__ bilW, const float* __restrict__ bilb,
    float* __restrict__ ft_vec){
  __shared__ float tv[512], pv[512];
  const int tid = threadIdx.x;
  const int kb = blockIdx.x, s = blockIdx.y;
  for (int idx=tid; idx<512; idx+=256){ tv[idx]=text_vec[s*512+idx]; pv[idx]=x_price[s*512+idx]; }
  __syncthreads();
  const int w = tid>>6, lane = tid&63;
  const int j = (lane&15)*4;
  const int ib = lane>>4;
  float4 pj[8];
  #pragma unroll
  for (int bb=0;bb<8;++bb) pj[bb] = *(const float4*)&pv[bb*64+j];
  const int k = kb*4 + w;
  const float* base = bilW + (size_t)(s*64+k)*4096;
  float acc[8] = {0,0,0,0,0,0,0,0};
  for (int it=0; it<16; ++it){
    float4 wv = *(const float4*)(base + it*256 + lane*4);
    int i = it*4 + ib;
    #pragma unroll
    for (int bb=0;bb<8;++bb){
      float partial = wv.x*pj[bb].x + wv.y*pj[bb].y + wv.z*pj[bb].z + wv.w*pj[bb].w;
      acc[bb] += partial * tv[bb*64+i];
    }
  }
  #pragma unroll
  for (int bb=0;bb<8;++bb){
    float tot = warp_sum(acc[bb]);
    if (lane==0) ft_vec[(size_t)(bb*87+s)*64 + k] = tanhf(tot + bilb[s*64+k]);
  }
}

// ---------------------------------------------------------------------------
__global__ __launch_bounds__(256) void k_gat_wh(
    const float* __restrict__ ft_vec, const float* __restrict__ gatW,
    const float* __restrict__ gata,
    float* __restrict__ Wh_g, float* __restrict__ a1h, float* __restrict__ a2h){
  __shared__ float ftb[5568];
  __shared__ float Ws[4096];
  const int tid = threadIdx.x;
  const int hd = blockIdx.x>>3, b = blockIdx.x&7;
  for (int idx=tid; idx<5568; idx+=256) ftb[idx] = ft_vec[(size_t)b*5568 + idx];
  for (int idx=tid; idx<4096; idx+=256) Ws[idx]  = gatW[(size_t)hd*4096 + idx];
  __syncthreads();
  const int f = tid&63, sq = tid>>6;
  const float af1 = gata[hd*128 + f], af2 = gata[hd*128 + 64 + f];
  for (int p=0;p<22;++p){
    int ss = p*4 + sq;
    if (ss < 87){
      float acc = 0.f;
      #pragma unroll 16
      for (int k=0;k<64;++k) acc += ftb[ss*64+k]*Ws[k*64+f];
      Wh_g[(size_t)((hd*8+b)*87 + ss)*64 + f] = acc;
      float p1 = warp_sum(acc*af1);
      float p2 = warp_sum(acc*af2);
      if (f==0){ a1h[(hd*8+b)*87 + ss] = p1; a2h[(hd*8+b)*87 + ss] = p2; }
    }
  }
}

__global__ __launch_bounds__(256) void k_gat_att(
    const float* __restrict__ Wh_g, const float* __restrict__ a1h,
    const float* __restrict__ a2h, const float* __restrict__ adj,
    float* __restrict__ xg){
  __shared__ float whs[5568];
  __shared__ float a1s[96], a2s[96];
  __shared__ float adjs[7569];
  __shared__ float attw[4*128];
  const int tid = threadIdx.x;
  const int hd = blockIdx.x>>3, b = blockIdx.x&7;
  const int hb = hd*8+b;
  for (int idx=tid; idx<5568; idx+=256) whs[idx] = Wh_g[(size_t)hb*5568 + idx];
  for (int idx=tid; idx<87;   idx+=256){ a1s[idx]=a1h[hb*87+idx]; a2s[idx]=a2h[hb*87+idx]; }
  for (int idx=tid; idx<7569; idx+=256) adjs[idx]=adj[idx];
  __syncthreads();
  const int w = tid>>6, lane = tid&63;
  for (int i=0;i<22;++i){
    int n = w + 4*i;
    if (n < 87){
      float a1n = a1s[n];
      float x1 = a1n + a2s[lane];
      float e1 = (adjs[n*87+lane] > 0.f) ? (x1>0.f? x1 : 0.2f*x1) : -9e15f;
      float e2 = -INFINITY;
      if (lane < 23){
        float x2 = a1n + a2s[64+lane];
        e2 = (adjs[n*87+64+lane] > 0.f) ? (x2>0.f? x2 : 0.2f*x2) : -9e15f;
      }
      float mx  = warp_max(fmaxf(e1,e2));
      float ex1 = expf(e1-mx);
      float ex2 = (lane<23) ? expf(e2-mx) : 0.f;
      float inv = 1.f/warp_sum(ex1+ex2);
      attw[w*128+lane] = ex1*inv;
      if (lane<23) attw[w*128+64+lane] = ex2*inv;
      float o = 0.f;
      for (int m=0;m<87;++m) o += attw[w*128+m]*whs[m*64+lane];
      float val = (o>0.f) ? o : expm1f(o);
      xg[(size_t)(b*87+n)*512 + hd*64 + lane] = val;
    }
  }
}

// ---------------------------------------------------------------------------
__global__ __launch_bounds__(256) void k_final(
    const float* __restrict__ xg, const float* __restrict__ ft_vec,
    const float* __restrict__ outW, const float* __restrict__ outa,
    const float* __restrict__ lxW, const float* __restrict__ lxb,
    const float* __restrict__ lpW, const float* __restrict__ lpb,
    const float* __restrict__ adj, float* __restrict__ out){
  __shared__ float whs2[176];
  __shared__ float a1s[96], a2s[96];
  const int tid = threadIdx.x;
  const int b = blockIdx.x;
  const int w = tid>>6, lane = tid&63;
  for (int item=w; item<174; item+=4){
    int ss = item>>1, c = item&1;
    const float* xr = xg + (size_t)(b*87+ss)*512;
    float a = 0.f;
    #pragma unroll
    for (int kk=0;kk<8;++kk) a += xr[kk*64+lane]*outW[(kk*64+lane)*2+c];
    a = warp_sum(a);
    if (lane==0) whs2[item] = a;
  }
  __syncthreads();
  for (int idx=tid; idx<87; idx+=256){
    a1s[idx] = whs2[idx*2]*outa[0] + whs2[idx*2+1]*outa[1];
    a2s[idx] = whs2[idx*2]*outa[2] + whs2[idx*2+1]*outa[3];
  }
  __syncthreads();
  for (int i=0;i<22;++i){
    int n = w + 4*i;
    if (n<87){
      float a1n = a1s[n];
      float x1 = a1n + a2s[lane];
      float e1 = (adj[n*87+lane]>0.f) ? (x1>0.f?x1:0.2f*x1) : -9e15f;
      float e2 = -INFINITY;
      if (lane<23){
        float x2 = a1n + a2s[64+lane];
        e2 = (adj[n*87+64+lane]>0.f) ? (x2>0.f?x2:0.2f*x2) : -9e15f;
      }
      float mx  = warp_max(fmaxf(e1,e2));
      float ex1 = expf(e1-mx);
      float ex2 = (lane<23)?expf(e2-mx):0.f;
      float inv = 1.f/warp_sum(ex1+ex2);
      float at1 = ex1*inv, at2 = ex2*inv;
      float p0 = at1*whs2[lane*2];
      float p1 = at1*whs2[lane*2+1];
      if (lane<23){ p0 += at2*whs2[(64+lane)*2]; p1 += at2*whs2[(64+lane)*2+1]; }
      float s0 = warp_sum(p0);
      float s1 = warp_sum(p1);
      float ftv = ft_vec[(size_t)(b*87+n)*64 + lane];
      float d0 = warp_sum(ftv*lxW[lane]);
      float d1 = warp_sum(ftv*lxW[64+lane]);
      float dp = warp_sum(ftv*lpW[lane]);
      if (lane==0){
        float ep  = tanhf(dp + lpb[0])*0.01f;
        float o10 = tanhf(d0 + lxb[0]);
        float o11 = tanhf(d1 + lxb[1]);
        float g0 = (s0>0.f)?s0:expm1f(s0);
        float g1 = (s1>0.f)?s1:expm1f(s1);
        float* op = out + (size_t)(b*87+n)*3;
        op[0] = ep; op[1] = g0 + o10; op[2] = g1 + o11;
      }
    }
  }
}

// ---------------------------------------------------------------------------
extern "C" void kernel_launch(void* const* d_in, const int* in_sizes, int n_in,
                              void* d_out, int out_size, void* d_ws, size_t ws_size,
                              hipStream_t stream){
  const float* text      = (const float*)d_in[0];
  const float* price     = (const float*)d_in[1];
  const float* adj       = (const float*)d_in[2];
  const float* grup_Wih  = (const float*)d_in[4];
  const float* grup_Whh  = (const float*)d_in[5];
  const float* grup_bih  = (const float*)d_in[6];
  const float* grup_bhh  = (const float*)d_in[7];
  const float* tgru_Wih  = (const float*)d_in[8];
  const float* tgru_Whh  = (const float*)d_in[9];
  const float* tgru_bih  = (const float*)d_in[10];
  const float* tgru_bhh  = (const float*)d_in[11];
  const float* grut_Wih  = (const float*)d_in[12];
  const float* grut_Whh  = (const float*)d_in[13];
  const float* grut_bih  = (const float*)d_in[14];
  const float* grut_bhh  = (const float*)d_in[15];
  const float* attnp_W1  = (const float*)d_in[16];
  const float* attnp_b1  = (const float*)d_in[17];
  const float* attnp_W2  = (const float*)d_in[18];
  const float* attnp_b2  = (const float*)d_in[19];
  const float* attnp_V   = (const float*)d_in[20];
  const float* attnp_bV  = (const float*)d_in[21];
  const float* attw_W1   = (const float*)d_in[22];
  const float* attw_b1   = (const float*)d_in[23];
  const float* attw_W2   = (const float*)d_in[24];
  const float* attw_b2   = (const float*)d_in[25];
  const float* attw_V    = (const float*)d_in[26];
  const float* attw_bV   = (const float*)d_in[27];
  const float* attnt_W1  = (const float*)d_in[28];
  const float* attnt_b1  = (const float*)d_in[29];
  const float* attnt_W2  = (const float*)d_in[30];
  const float* attnt_b2  = (const float*)d_in[31];
  const float* attnt_V   = (const float*)d_in[32];
  const float* attnt_bV  = (const float*)d_in[33];
  const float* bil_W     = (const float*)d_in[34];
  const float* bil_b     = (const float*)d_in[35];
  const float* lx_W      = (const float*)d_in[36];
  const float* lx_b      = (const float*)d_in[37];
  const float* lp_W      = (const float*)d_in[38];
  const float* lp_b      = (const float*)d_in[39];
  const float* gat_W     = (const float*)d_in[40];
  const float* gat_a     = (const float*)d_in[41];
  const float* out_W     = (const float*)d_in[42];
  const float* out_a     = (const float*)d_in[43];

  float* ws       = (float*)d_ws;
  float* xi_t     = ws;                      // 20,044,800
  float* full_t   = xi_t   + 20044800;       //  6,681,600
  float* news     = full_t + 6681600;        //    222,720
  float* x_price  = news   + 222720;         //     44,544
  float* text_vec = x_price + 44544;         //     44,544
  float* ft_vec   = text_vec + 44544;        //     44,544
  float* Wh_g     = ft_vec + 44544;          //  2,850,816
  float* a1h      = Wh_g   + 2850816;        //      5,568
  float* a2h      = a1h    + 5568;           //      5,568
  float* xg       = a2h    + 5568;           //    356,352
  float* q        = Wh_g;                    // alias (disjoint lifetime)

  k_tweet_proj<<<dim3(3,5,87),256,0,stream>>>(text, tgru_Wih, tgru_bih, xi_t);
  k_gru30<<<435,384,0,stream>>>(xi_t, tgru_Whh, tgru_bhh, attw_W1, attw_b1, full_t, q);
  k_uproj<<<435,256,0,stream>>>(full_t, q, attw_W2, attw_b2, attw_V, attw_bV, news);
  k_stock<<<174,384,0,stream>>>(price, news,
      grup_Wih, grup_Whh, grup_bih, grup_bhh,
      attnp_W1, attnp_b1, attnp_W2, attnp_b2, attnp_V, attnp_bV,
      grut_Wih, grut_Whh, grut_bih, grut_bhh,
      attnt_W1, attnt_b1, attnt_W2, attnt_b2, attnt_V, attnt_bV,
      x_price, text_vec);
  k_bilinear<<<dim3(16,87),256,0,stream>>>(text_vec, x_price, bil_W, bil_b, ft_vec);
  k_gat_wh<<<64,256,0,stream>>>(ft_vec, gat_W, gat_a, Wh_g, a1h, a2h);
  k_gat_att<<<64,256,0,stream>>>(Wh_g, a1h, a2h, adj, xg);
  k_final<<<8,256,0,stream>>>(xg, ft_vec, out_W, out_a, lx_W, lx_b, lp_W, lp_b,
      adj, (float*)d_out);
}

// Round 4
// 896.280 us; speedup vs baseline: 1.1435x; 1.1435x over previous
//
#include <hip/hip_runtime.h>
#include <math.h>

// Model dims: S=87, B=8, D=5, T=30, H=64, G=192, K_text=512

typedef short s16x8 __attribute__((ext_vector_type(8)));
typedef float f32x4 __attribute__((ext_vector_type(4)));

__device__ __forceinline__ float sigmoidf_(float x){ return 1.0f/(1.0f+expf(-x)); }

__device__ __forceinline__ float warp_sum(float v){
  #pragma unroll
  for (int off=32; off>0; off>>=1) v += __shfl_xor(v, off, 64);
  return v;
}
__device__ __forceinline__ float warp_max(float v){
  #pragma unroll
  for (int off=32; off>0; off>>=1) v = fmaxf(v, __shfl_xor(v, off, 64));
  return v;
}

__device__ __forceinline__ float readlane_f(float x, int k){
  return __int_as_float(__builtin_amdgcn_readlane(__float_as_int(x), k));
}

// truncation split: x ~= hi + lo with |err| ~ 2^-14 |x| (3 VALU ops/elem)
__device__ __forceinline__ void split_bf16(float x, unsigned short& hi, unsigned short& lo){
  unsigned u = __float_as_uint(x);
  hi = (unsigned short)(u >> 16);
  float r = x - __uint_as_float(u & 0xffff0000u);
  lo = (unsigned short)(__float_as_uint(r) >> 16);
}

union U8 { unsigned short u[8]; s16x8 v; };

// ---------------------------------------------------------------------------
// Kernel 1: tweet input projection via split-bf16 MFMA.
// 1-deep register prefetch (round-2 config: 88 VGPR, 5 waves/SIMD).
// NOTE: 2-deep ping-pong was tried and REGRESSED 144->299us (VGPR 144 ->
// occupancy 5->3 waves/SIMD; this kernel hides latency via TLP, not ILP).
// ---------------------------------------------------------------------------
__global__ __launch_bounds__(256) void k_tweet_proj(
    const float* __restrict__ text, const float* __restrict__ Wih,
    const float* __restrict__ bih, float* __restrict__ xi_t){
  __shared__ short lds[17408];   // Ah[2560] Al[2560] Bh[6144] Bl[6144] shorts = 34816 B
  const int tid = threadIdx.x;
  const int mb = blockIdx.x, d = blockIdx.y, s = blockIdx.z;
  const int lane = tid & 63, w = tid >> 6, quad = lane >> 4;

  const float* srcp[5]; int dsth[5]; int dstl[5]; bool val[5];
  #pragma unroll
  for (int i=0;i<5;++i){
    int c = tid + i*256;
    val[i] = (c < 1088);
    int cc = val[i] ? c : 0;
    int tile = cc>>6, slot = cc&63, k8 = slot>>4, i16 = slot&15;
    if (tile < 5){
      int row = mb*80 + tile*16 + i16;           // always < 240
      int b = row/30, t = row - b*30;
      srcp[i] = text + (size_t)(b*13050 + s*150 + d*30 + t)*512 + k8*8;
      dsth[i] = tile*512 + slot*8;
      dstl[i] = dsth[i] + 2560;
    } else {
      int g = (tile-5)*16 + i16;
      srcp[i] = Wih + (size_t)(s*192+g)*512 + k8*8;
      dsth[i] = 5120 + (tile-5)*512 + slot*8;
      dstl[i] = dsth[i] + 6144;
    }
  }

  f32x4 acc[5][3] = {};

  // prologue: preload chunk 0 into registers
  float4 v0[5], v1[5];
  #pragma unroll
  for (int i=0;i<5;++i){
    if (val[i]){
      v0[i] = *(const float4*)srcp[i];
      v1[i] = *(const float4*)(srcp[i]+4);
    }
  }

  for (int kc=0; kc<16; ++kc){
    __syncthreads();   // previous chunk's LDS reads done -> safe to overwrite
    #pragma unroll
    for (int i=0;i<5;++i){
      if (val[i]){
        float xs[8] = {v0[i].x,v0[i].y,v0[i].z,v0[i].w,v1[i].x,v1[i].y,v1[i].z,v1[i].w};
        U8 hv, lv;
        #pragma unroll
        for (int j=0;j<8;++j) split_bf16(xs[j], hv.u[j], lv.u[j]);
        *(s16x8*)&lds[dsth[i]] = hv.v;
        *(s16x8*)&lds[dstl[i]] = lv.v;
        if (kc < 15){
          const float* sp = srcp[i] + (kc+1)*32;
          v0[i] = *(const float4*)sp;
          v1[i] = *(const float4*)(sp+4);
        }
      }
    }
    __syncthreads();
    s16x8 ah[5], al[5], bh[3], bl[3];
    #pragma unroll
    for (int mt=0;mt<5;++mt){
      ah[mt] = *(const s16x8*)&lds[mt*512 + lane*8];
      al[mt] = *(const s16x8*)&lds[2560 + mt*512 + lane*8];
    }
    #pragma unroll
    for (int nl=0;nl<3;++nl){
      int nt = w*3+nl;
      bh[nl] = *(const s16x8*)&lds[5120 + nt*512 + lane*8];
      bl[nl] = *(const s16x8*)&lds[11264 + nt*512 + lane*8];
    }
    #pragma unroll
    for (int mt=0;mt<5;++mt){
      #pragma unroll
      for (int nl=0;nl<3;++nl){
        acc[mt][nl] = __builtin_amdgcn_mfma_f32_16x16x32_bf16(ah[mt], bh[nl], acc[mt][nl], 0,0,0);
        acc[mt][nl] = __builtin_amdgcn_mfma_f32_16x16x32_bf16(ah[mt], bl[nl], acc[mt][nl], 0,0,0);
        acc[mt][nl] = __builtin_amdgcn_mfma_f32_16x16x32_bf16(al[mt], bh[nl], acc[mt][nl], 0,0,0);
      }
    }
  }

  // epilogue: C/D layout col=lane&15, row=quad*4+reg
  const size_t obase = (size_t)(s*5+d)*240;
  #pragma unroll
  for (int nl=0;nl<3;++nl){
    int g = (w*3+nl)*16 + (lane&15);
    float bias = bih[s*192+g];
    #pragma unroll
    for (int mt=0;mt<5;++mt){
      #pragma unroll
      for (int reg=0;reg<4;++reg){
        int row = mb*80 + mt*16 + quad*4 + reg;
        xi_t[(obase+row)*192 + g] = acc[mt][nl][reg] + bias;
      }
    }
  }
}

// ---------------------------------------------------------------------------
// Kernel 2: tweet GRU (30 steps), one block per (s,d).
// Weights register-resident (t-invariant); gate GEMV via v_readlane
// h-broadcast -> no LDS reads in the GEMV inner loop.
// ---------------------------------------------------------------------------
__global__ __launch_bounds__(384) void k_gru30(
    const float* __restrict__ xi_t, const float* __restrict__ Whh, const float* __restrict__ bhh,
    const float* __restrict__ W1, const float* __restrict__ b1,
    float* __restrict__ full_t, float* __restrict__ q){
  __shared__ float gh[1536];   // [b][192]
  __shared__ float h[544];     // [b][68]
  const int tid = threadIdx.x;
  const int bid = blockIdx.x;
  const int s = bid/5;
  const int lane = tid & 63;
  const int bh = tid / 192;        // 0 or 1
  const int g  = tid - bh*192;     // 0..191

  // weight registers: wv[kq] = Whh[s*192+g][kq*4 .. kq*4+3]
  float4 wv[16];
  {
    const float* wr = Whh + (size_t)(s*192+g)*64;
    #pragma unroll
    for (int kq=0;kq<16;++kq) wv[kq] = *(const float4*)(wr + kq*4);
  }
  const float bhhg = bhh[s*192+g];

  for (int idx=tid; idx<544; idx+=384) h[idx] = 0.f;

  const size_t sd240 = (size_t)bid*240;
  // apply-phase ownership: item idx=tid (if<512) and idx=tid+384 (tid<128)
  float xp[2][3]; float hprev[2] = {0.f, 0.f};
  #pragma unroll
  for (int u2=0;u2<2;++u2){
    int idx = tid + u2*384;
    if (idx < 512){
      int bb = idx>>6, j = idx&63;
      const float* xr = xi_t + (sd240 + bb*30 + 0)*192 + j;
      xp[u2][0]=xr[0]; xp[u2][1]=xr[64]; xp[u2][2]=xr[128];
    }
  }
  __syncthreads();

  float hreg[4] = {0.f,0.f,0.f,0.f};   // hreg[i] = h[bh*4+i][lane]

  for (int t=0; t<30; ++t){
    // ---- gate GEMV, all from registers ----
    float a0=bhhg, a1=bhhg, a2=bhhg, a3=bhhg;
    #pragma unroll
    for (int kq=0;kq<16;++kq){
      const float4 w4 = wv[kq];
      #pragma unroll
      for (int r=0;r<4;++r){
        const int k = kq*4 + r;
        const float wk = (r==0)?w4.x:(r==1)?w4.y:(r==2)?w4.z:w4.w;
        a0 = fmaf(readlane_f(hreg[0], k), wk, a0);
        a1 = fmaf(readlane_f(hreg[1], k), wk, a1);
        a2 = fmaf(readlane_f(hreg[2], k), wk, a2);
        a3 = fmaf(readlane_f(hreg[3], k), wk, a3);
      }
    }
    gh[(bh*4+0)*192 + g] = a0;
    gh[(bh*4+1)*192 + g] = a1;
    gh[(bh*4+2)*192 + g] = a2;
    gh[(bh*4+3)*192 + g] = a3;
    __syncthreads();

    // ---- gate apply ----
    float cur[2][3];
    #pragma unroll
    for (int u2=0;u2<2;++u2){ cur[u2][0]=xp[u2][0]; cur[u2][1]=xp[u2][1]; cur[u2][2]=xp[u2][2]; }
    if (t < 29){
      #pragma unroll
      for (int u2=0;u2<2;++u2){
        int idx = tid + u2*384;
        if (idx < 512){
          int bb = idx>>6, j = idx&63;
          const float* xr = xi_t + (sd240 + bb*30 + t + 1)*192 + j;
          xp[u2][0]=xr[0]; xp[u2][1]=xr[64]; xp[u2][2]=xr[128];
        }
      }
    }
    #pragma unroll
    for (int u2=0;u2<2;++u2){
      int idx = tid + u2*384;
      if (idx < 512){
        int bb = idx>>6, j = idx&63;
        float r = sigmoidf_(cur[u2][0] + gh[bb*192+j]);
        float z = sigmoidf_(cur[u2][1] + gh[bb*192+64+j]);
        float n = tanhf(   cur[u2][2] + r*gh[bb*192+128+j]);
        float hn = (1.f - z)*n + z*hprev[u2];
        hprev[u2] = hn;
        h[bb*68+j] = hn;
        full_t[(sd240 + bb*30 + t)*64 + j] = hn;
      }
    }
    __syncthreads();
    // reload h broadcast registers for next step's GEMV
    hreg[0] = h[(bh*4+0)*68 + lane];
    hreg[1] = h[(bh*4+1)*68 + lane];
    hreg[2] = h[(bh*4+2)*68 + lane];
    hreg[3] = h[(bh*4+3)*68 + lane];
  }

  // q = W1 h_last + b1
  for (int idx=tid; idx<512; idx+=384){
    int bb = idx>>6, j = idx&63;
    float acc = b1[s*64+j];
    const float* wr = W1 + (size_t)(s*64+j)*64;
    #pragma unroll
    for (int kq=0;kq<16;++kq){
      float4 w4 = *(const float4*)(wr+kq*4);
      acc += h[bb*68+kq*4+0]*w4.x + h[bb*68+kq*4+1]*w4.y
           + h[bb*68+kq*4+2]*w4.z + h[bb*68+kq*4+3]*w4.w;
    }
    q[(size_t)bid*512 + idx] = acc;
  }
}

// ---------------------------------------------------------------------------
// Kernel 3: attention projection u = full_t @ W2^T via split-bf16 MFMA, fused
// with score=V.tanh(q+u+b2)+bV, softmax over T, weighted sum -> news.
// ---------------------------------------------------------------------------
__global__ __launch_bounds__(256) void k_uproj(
    const float* __restrict__ full_t, const float* __restrict__ q,
    const float* __restrict__ W2, const float* __restrict__ b2,
    const float* __restrict__ V, const float* __restrict__ bV,
    float* __restrict__ news){
  __shared__ short lds[19456];   // Ah[7680] Al[7680] Bh[2048] Bl[2048] = 38912 B
  float* scpart = (float*)&lds[15360];
  float* ssc = scpart + 960;
  float* swt = ssc + 240;
  const int tid = threadIdx.x, lane = tid&63, w = tid>>6, quad = lane>>4;
  const int bid = blockIdx.x;
  const int s = bid/5;
  const size_t sd240 = (size_t)bid*240;

  const float* srcp2[5]; int dh2[5]; int ldo2[5]; bool val2[5];
  #pragma unroll
  for (int i=0;i<5;++i){
    int idx = tid + i*256;
    val2[i] = (idx < 1216);
    int ix = val2[i] ? idx : 0;
    if (ix < 960){
      int r = ix>>2, kc8 = ix&3;
      srcp2[i] = full_t + (sd240 + r)*64 + kc8*8;
      dh2[i] = ((r>>4)*64 + ((r&15)|(kc8<<4)))*8; ldo2[i] = 7680;
    } else {
      int c = ix - 960; int j = c>>2, kc8 = c&3;
      srcp2[i] = W2 + (size_t)(s*64+j)*64 + kc8*8;
      dh2[i] = 15360 + ((j>>4)*64 + ((j&15)|(kc8<<4)))*8; ldo2[i] = 2048;
    }
  }

  float4 w0r[5], w1r[5];
  #pragma unroll
  for (int i=0;i<5;++i){
    if (val2[i]){
      w0r[i] = *(const float4*)srcp2[i];
      w1r[i] = *(const float4*)(srcp2[i]+4);
    }
  }

  f32x4 acc[15] = {};
  for (int kc=0; kc<2; ++kc){
    __syncthreads();
    #pragma unroll
    for (int i=0;i<5;++i){
      if (val2[i]){
        float xs[8] = {w0r[i].x,w0r[i].y,w0r[i].z,w0r[i].w,w1r[i].x,w1r[i].y,w1r[i].z,w1r[i].w};
        U8 hv, lv;
        #pragma unroll
        for (int j2=0;j2<8;++j2) split_bf16(xs[j2], hv.u[j2], lv.u[j2]);
        *(s16x8*)&lds[dh2[i]] = hv.v;
        *(s16x8*)&lds[dh2[i]+ldo2[i]] = lv.v;
        if (kc == 0){
          const float* sp = srcp2[i] + 32;
          w0r[i] = *(const float4*)sp;
          w1r[i] = *(const float4*)(sp+4);
        }
      }
    }
    __syncthreads();
    s16x8 bh = *(const s16x8*)&lds[15360 + (w*64+lane)*8];
    s16x8 bl = *(const s16x8*)&lds[17408 + (w*64+lane)*8];
    #pragma unroll
    for (int mt=0;mt<15;++mt){
      s16x8 ah = *(const s16x8*)&lds[(mt*64+lane)*8];
      s16x8 al = *(const s16x8*)&lds[7680+(mt*64+lane)*8];
      acc[mt] = __builtin_amdgcn_mfma_f32_16x16x32_bf16(ah, bh, acc[mt], 0,0,0);
      acc[mt] = __builtin_amdgcn_mfma_f32_16x16x32_bf16(ah, bl, acc[mt], 0,0,0);
      acc[mt] = __builtin_amdgcn_mfma_f32_16x16x32_bf16(al, bh, acc[mt], 0,0,0);
    }
  }
  __syncthreads();

  {
    int j = w*16 + (lane&15);
    float Vj = V[s*64+j], b2j = b2[s*64+j];
    const float* qb = q + (size_t)bid*512;
    #pragma unroll
    for (int mt=0;mt<15;++mt){
      #pragma unroll
      for (int reg=0;reg<4;++reg){
        int row = mt*16 + quad*4 + reg;
        int bb = row/30;
        float val = tanhf(acc[mt][reg] + b2j + qb[bb*64+j]) * Vj;
        val += __shfl_xor(val, 1, 64);
        val += __shfl_xor(val, 2, 64);
        val += __shfl_xor(val, 4, 64);
        val += __shfl_xor(val, 8, 64);
        if ((lane&15)==0) scpart[w*240 + row] = val;
      }
    }
  }
  __syncthreads();
  float bVs = bV[s];
  for (int idx=tid; idx<240; idx+=256)
    ssc[idx] = scpart[idx] + scpart[240+idx] + scpart[480+idx] + scpart[720+idx] + bVs;
  __syncthreads();
  if (tid < 8){
    float mx = -1e30f;
    for (int t=0;t<30;++t) mx = fmaxf(mx, ssc[tid*30+t]);
    float ssum = 0.f;
    for (int t=0;t<30;++t){ float e = expf(ssc[tid*30+t]-mx); swt[tid*30+t] = e; ssum += e; }
    float inv = 1.f/ssum;
    for (int t=0;t<30;++t) swt[tid*30+t] *= inv;
  }
  __syncthreads();
  for (int idx=tid; idx<512; idx+=256){
    int bb = idx>>6, jj = idx&63;
    float a = 0.f;
    for (int t=0;t<30;++t) a += swt[bb*30+t]*full_t[(sd240 + bb*30 + t)*64 + jj];
    news[(size_t)bid*512 + idx] = a;
  }
}

// ---------------------------------------------------------------------------
// Fused stock kernel: replaces k_price (blocks 0..86) and k_day (87..173).
// ---------------------------------------------------------------------------
__global__ __launch_bounds__(384) void k_stock(
    const float* __restrict__ price, const float* __restrict__ news,
    const float* __restrict__ pWih, const float* __restrict__ pWhh,
    const float* __restrict__ pbih, const float* __restrict__ pbhh,
    const float* __restrict__ pW1, const float* __restrict__ pb1,
    const float* __restrict__ pW2, const float* __restrict__ pb2,
    const float* __restrict__ pV, const float* __restrict__ pbV,
    const float* __restrict__ dWih, const float* __restrict__ dWhh,
    const float* __restrict__ dbih, const float* __restrict__ dbhh,
    const float* __restrict__ dW1, const float* __restrict__ db1,
    const float* __restrict__ dW2, const float* __restrict__ db2,
    const float* __restrict__ dV, const float* __restrict__ dbV,
    float* __restrict__ x_price, float* __restrict__ text_vec){
  __shared__ float sm[27904];          // 111.6 KB
  float* Wt  = sm;            // 12288: transposed Wih, then Whh, then W2t reuse
  float* xi  = sm + 12288;    // 7680
  float* full= sm + 19968;    // 2560
  float* h   = sm + 22528;    // 544 (8 x 68)
  float* gh  = sm + 23072;    // 1568 (8 x 196); tail reuse: Vs/b2s/sc/wsm
  float* nw  = sm + 24640;    // 2560
  float* bihs= sm + 27200;    // 192
  float* qq  = sm + 27392;    // 512

  const int tid = threadIdx.x;
  const int bid = blockIdx.x;
  const bool isday = (bid >= 87);
  const int s = isday ? (bid - 87) : bid;

  const float* Wih = isday ? dWih : pWih;
  const float* Whh = isday ? dWhh : pWhh;
  const float* bih = isday ? dbih : pbih;
  const float* bhh = isday ? dbhh : pbhh;
  const float* W1  = isday ? dW1  : pW1;
  const float* b1  = isday ? db1  : pb1;
  const float* W2  = isday ? dW2  : pW2;
  const float* b2  = isday ? db2  : pb2;
  const float* V   = isday ? dV   : pV;
  const float* bV  = isday ? dbV  : pbV;

  // ---- phase A: stage inputs, zero h, stage bih, stage Wih (transposed) ----
  if (isday){
    for (int idx=tid; idx<2560; idx+=384) nw[idx] = news[(size_t)s*2560 + idx];
    for (int idx=tid; idx<3072; idx+=384){
      int g = idx>>4, kq = idx&15;
      float4 wv = *(const float4*)&Wih[(size_t)(s*192+g)*64 + kq*4];
      Wt[(kq*4+0)*192+g]=wv.x; Wt[(kq*4+1)*192+g]=wv.y;
      Wt[(kq*4+2)*192+g]=wv.z; Wt[(kq*4+3)*192+g]=wv.w;
    }
  } else {
    for (int idx=tid; idx<120; idx+=384){
      int bb = idx/15, rem = idx - bb*15; int dd = rem/3, k = rem - dd*3;
      nw[idx] = price[(size_t)((bb*87+s)*5+dd)*3 + k];
    }
    for (int idx=tid; idx<576; idx+=384) Wt[idx] = Wih[(size_t)s*576 + idx]; // [g][3]
  }
  for (int idx=tid; idx<544; idx+=384) h[idx] = 0.f;
  for (int idx=tid; idx<192; idx+=384) bihs[idx] = bih[s*192+idx];
  __syncthreads();

  // ---- phase B: xi[bd*192+g] from LDS only ----
  if (isday){
    for (int idx=tid; idx<7680; idx+=384){
      int bd = idx/192, g = idx - bd*192;
      int bb = bd/5, dd = bd - bb*5;
      const float* xr = nw + (dd*8+bb)*64;
      float a0=0.f,a1=0.f,a2=0.f,a3=0.f;
      #pragma unroll
      for (int k=0;k<64;k+=4){
        a0 += xr[k]  *Wt[(k  )*192+g];
        a1 += xr[k+1]*Wt[(k+1)*192+g];
        a2 += xr[k+2]*Wt[(k+2)*192+g];
        a3 += xr[k+3]*Wt[(k+3)*192+g];
      }
      xi[idx] = bihs[g] + ((a0+a1)+(a2+a3));
    }
  } else {
    for (int idx=tid; idx<7680; idx+=384){
      int bd = idx/192, g = idx - bd*192;
      xi[idx] = bihs[g] + nw[bd*3]*Wt[g*3] + nw[bd*3+1]*Wt[g*3+1] + nw[bd*3+2]*Wt[g*3+2];
    }
  }
  __syncthreads();

  // ---- phase C: stage Whh transposed (overwrite Wt) ----
  for (int idx=tid; idx<3072; idx+=384){
    int g = idx>>4, kq = idx&15;
    float4 wv = *(const float4*)&Whh[(size_t)(s*192+g)*64 + kq*4];
    Wt[(kq*4+0)*192+g]=wv.x; Wt[(kq*4+1)*192+g]=wv.y;
    Wt[(kq*4+2)*192+g]=wv.z; Wt[(kq*4+3)*192+g]=wv.w;
  }
  const int gq = tid>>3, b = tid&7;        // gq 0..47, b 0..7
  float4 bh4 = *(const float4*)&bhh[s*192 + gq*4];
  __syncthreads();

  // ---- phase D: 5 GRU steps ----
  for (int dd=0; dd<5; ++dd){
    float4 acc = bh4;
    #pragma unroll
    for (int kq=0;kq<16;++kq){
      float4 h4 = *(const float4*)&h[b*68+kq*4];
      float4 w0 = *(const float4*)&Wt[(kq*4+0)*192+gq*4];
      float4 w1 = *(const float4*)&Wt[(kq*4+1)*192+gq*4];
      float4 w2 = *(const float4*)&Wt[(kq*4+2)*192+gq*4];
      float4 w3 = *(const float4*)&Wt[(kq*4+3)*192+gq*4];
      acc.x += h4.x*w0.x + h4.y*w1.x + h4.z*w2.x + h4.w*w3.x;
      acc.y += h4.x*w0.y + h4.y*w1.y + h4.z*w2.y + h4.w*w3.y;
      acc.z += h4.x*w0.z + h4.y*w1.z + h4.z*w2.z + h4.w*w3.z;
      acc.w += h4.x*w0.w + h4.y*w1.w + h4.z*w2.w + h4.w*w3.w;
    }
    *(float4*)&gh[b*196+gq*4] = acc;
    __syncthreads();
    for (int idx=tid; idx<512; idx+=384){
      int bb = idx>>6, j = idx&63;
      const float* xr = xi + (bb*5+dd)*192;
      float r = sigmoidf_(xr[j]     + gh[bb*196+j]);
      float z = sigmoidf_(xr[64+j]  + gh[bb*196+64+j]);
      float n = tanhf(   xr[128+j] + r*gh[bb*196+128+j]);
      float hv = h[bb*68+j];
      float hn = (1.f-z)*n + z*hv;
      h[bb*68+j] = hn;
      full[(bb*5+dd)*64 + j] = hn;
    }
    __syncthreads();
  }

  // ---- phase E: Bahdanau attention over D=5 ----
  float* W2t = Wt;                 // 4096, gates done
  float* Vs  = gh;                 // 64
  float* b2s = gh + 64;            // 64
  float* sc  = gh + 128;           // 40
  float* wsm = gh + 168;           // 40
  for (int idx=tid; idx<512; idx+=384){
    int bb = idx>>6, j = idx&63;
    float a0=0.f,a1=0.f,a2=0.f,a3=0.f;
    float accq = b1[s*64+j];
    const float* wr = W1 + (size_t)(s*64+j)*64;
    #pragma unroll
    for (int kq=0;kq<16;++kq){
      float4 w4 = *(const float4*)(wr+kq*4);
      a0 += h[bb*68+kq*4+0]*w4.x; a1 += h[bb*68+kq*4+1]*w4.y;
      a2 += h[bb*68+kq*4+2]*w4.z; a3 += h[bb*68+kq*4+3]*w4.w;
    }
    qq[idx] = accq + ((a0+a1)+(a2+a3));
  }
  for (int idx=tid; idx<1024; idx+=384){
    int j = idx>>4, kq = idx&15;
    float4 w4 = *(const float4*)&W2[(size_t)(s*64+j)*64 + kq*4];
    W2t[(kq*4+0)*64+j]=w4.x; W2t[(kq*4+1)*64+j]=w4.y;
    W2t[(kq*4+2)*64+j]=w4.z; W2t[(kq*4+3)*64+j]=w4.w;
  }
  for (int idx=tid; idx<64; idx+=384){ Vs[idx]=V[s*64+idx]; b2s[idx]=b2[s*64+idx]; }
  __syncthreads();
  const int w = tid>>6, lane = tid&63;
  const float bVs = bV[s];
  for (int pair=w; pair<40; pair+=6){
    int bb = pair/5, dd = pair - bb*5;
    const float* fr = full + (bb*5+dd)*64;
    float u0=0.f,u1=0.f,u2=0.f,u3=0.f;
    #pragma unroll
    for (int k=0;k<64;k+=4){
      u0 += W2t[(k  )*64+lane]*fr[k];
      u1 += W2t[(k+1)*64+lane]*fr[k+1];
      u2 += W2t[(k+2)*64+lane]*fr[k+2];
      u3 += W2t[(k+3)*64+lane]*fr[k+3];
    }
    float u = qq[bb*64+lane] + b2s[lane] + ((u0+u1)+(u2+u3));
    float p = warp_sum(tanhf(u)*Vs[lane]);
    if (lane==0) sc[pair] = p + bVs;
  }
  __syncthreads();
  if (tid<8){
    float mx=-1e30f; for (int dd=0;dd<5;++dd) mx=fmaxf(mx, sc[tid*5+dd]);
    float ssum=0.f;
    for (int dd=0;dd<5;++dd){ float e=expf(sc[tid*5+dd]-mx); wsm[tid*5+dd]=e; ssum+=e; }
    float inv=1.f/ssum;
    for (int dd=0;dd<5;++dd) wsm[tid*5+dd]*=inv;
  }
  __syncthreads();
  float* outv = isday ? text_vec : x_price;
  for (int idx=tid; idx<512; idx+=384){
    int bb=idx>>6, j=idx&63;
    float acc=0.f;
    for (int dd=0;dd<5;++dd) acc += wsm[bb*5+dd]*full[(bb*5+dd)*64+j];
    outv[(size_t)(s*8+bb)*64 + j] = acc;
  }
}

// ---------------------------------------------------------------------------
__global__ __launch_bounds__(256) void k_bilinear(
    const float* __restrict__ text_vec, const float* __restrict__ x_price,
    const float* __restrict__ bilW, const float* __restrict__ bilb,
    float* __restrict__ ft_vec){
  __shared__ float tv[512], pv[512];
  const int tid = threadIdx.x;
  const int kb = blockIdx.x, s = blockIdx.y;
  for (int idx=tid; idx<512; idx+=256){ tv[idx]=text_vec[s*512+idx]; pv[idx]=x_price[s*512+idx]; }
  __syncthreads();
  const int w = tid>>6, lane = tid&63;
  const int j = (lane&15)*4;
  const int ib = lane>>4;
  float4 pj[8];
  #pragma unroll
  for (int bb=0;bb<8;++bb) pj[bb] = *(const float4*)&pv[bb*64+j];
  const int k = kb*4 + w;
  const float* base = bilW + (size_t)(s*64+k)*4096;
  float acc[8] = {0,0,0,0,0,0,0,0};
  for (int it=0; it<16; ++it){
    float4 wv = *(const float4*)(base + it*256 + lane*4);
    int i = it*4 + ib;
    #pragma unroll
    for (int bb=0;bb<8;++bb){
      float partial = wv.x*pj[bb].x + wv.y*pj[bb].y + wv.z*pj[bb].z + wv.w*pj[bb].w;
      acc[bb] += partial * tv[bb*64+i];
    }
  }
  #pragma unroll
  for (int bb=0;bb<8;++bb){
    float tot = warp_sum(acc[bb]);
    if (lane==0) ft_vec[(size_t)(bb*87+s)*64 + k] = tanhf(tot + bilb[s*64+k]);
  }
}

// ---------------------------------------------------------------------------
__global__ __launch_bounds__(256) void k_gat_wh(
    const float* __restrict__ ft_vec, const float* __restrict__ gatW,
    const float* __restrict__ gata,
    float* __restrict__ Wh_g, float* __restrict__ a1h, float* __restrict__ a2h){
  __shared__ float ftb[5568];
  __shared__ float Ws[4096];
  const int tid = threadIdx.x;
  const int hd = blockIdx.x>>3, b = blockIdx.x&7;
  for (int idx=tid; idx<5568; idx+=256) ftb[idx] = ft_vec[(size_t)b*5568 + idx];
  for (int idx=tid; idx<4096; idx+=256) Ws[idx]  = gatW[(size_t)hd*4096 + idx];
  __syncthreads();
  const int f = tid&63, sq = tid>>6;
  const float af1 = gata[hd*128 + f], af2 = gata[hd*128 + 64 + f];
  for (int p=0;p<22;++p){
    int ss = p*4 + sq;
    if (ss < 87){
      float acc = 0.f;
      #pragma unroll 16
      for (int k=0;k<64;++k) acc += ftb[ss*64+k]*Ws[k*64+f];
      Wh_g[(size_t)((hd*8+b)*87 + ss)*64 + f] = acc;
      float p1 = warp_sum(acc*af1);
      float p2 = warp_sum(acc*af2);
      if (f==0){ a1h[(hd*8+b)*87 + ss] = p1; a2h[(hd*8+b)*87 + ss] = p2; }
    }
  }
}

__global__ __launch_bounds__(256) void k_gat_att(
    const float* __restrict__ Wh_g, const float* __restrict__ a1h,
    const float* __restrict__ a2h, const float* __restrict__ adj,
    float* __restrict__ xg){
  __shared__ float whs[5568];
  __shared__ float a1s[96], a2s[96];
  __shared__ float adjs[7569];
  __shared__ float attw[4*128];
  const int tid = threadIdx.x;
  const int hd = blockIdx.x>>3, b = blockIdx.x&7;
  const int hb = hd*8+b;
  for (int idx=tid; idx<5568; idx+=256) whs[idx] = Wh_g[(size_t)hb*5568 + idx];
  for (int idx=tid; idx<87;   idx+=256){ a1s[idx]=a1h[hb*87+idx]; a2s[idx]=a2h[hb*87+idx]; }
  for (int idx=tid; idx<7569; idx+=256) adjs[idx]=adj[idx];
  __syncthreads();
  const int w = tid>>6, lane = tid&63;
  for (int i=0;i<22;++i){
    int n = w + 4*i;
    if (n < 87){
      float a1n = a1s[n];
      float x1 = a1n + a2s[lane];
      float e1 = (adjs[n*87+lane] > 0.f) ? (x1>0.f? x1 : 0.2f*x1) : -9e15f;
      float e2 = -INFINITY;
      if (lane < 23){
        float x2 = a1n + a2s[64+lane];
        e2 = (adjs[n*87+64+lane] > 0.f) ? (x2>0.f? x2 : 0.2f*x2) : -9e15f;
      }
      float mx  = warp_max(fmaxf(e1,e2));
      float ex1 = expf(e1-mx);
      float ex2 = (lane<23) ? expf(e2-mx) : 0.f;
      float inv = 1.f/warp_sum(ex1+ex2);
      attw[w*128+lane] = ex1*inv;
      if (lane<23) attw[w*128+64+lane] = ex2*inv;
      float o = 0.f;
      for (int m=0;m<87;++m) o += attw[w*128+m]*whs[m*64+lane];
      float val = (o>0.f) ? o : expm1f(o);
      xg[(size_t)(b*87+n)*512 + hd*64 + lane] = val;
    }
  }
}

// ---------------------------------------------------------------------------
__global__ __launch_bounds__(256) void k_final(
    const float* __restrict__ xg, const float* __restrict__ ft_vec,
    const float* __restrict__ outW, const float* __restrict__ outa,
    const float* __restrict__ lxW, const float* __restrict__ lxb,
    const float* __restrict__ lpW, const float* __restrict__ lpb,
    const float* __restrict__ adj, float* __restrict__ out){
  __shared__ float whs2[176];
  __shared__ float a1s[96], a2s[96];
  const int tid = threadIdx.x;
  const int b = blockIdx.x;
  const int w = tid>>6, lane = tid&63;
  for (int item=w; item<174; item+=4){
    int ss = item>>1, c = item&1;
    const float* xr = xg + (size_t)(b*87+ss)*512;
    float a = 0.f;
    #pragma unroll
    for (int kk=0;kk<8;++kk) a += xr[kk*64+lane]*outW[(kk*64+lane)*2+c];
    a = warp_sum(a);
    if (lane==0) whs2[item] = a;
  }
  __syncthreads();
  for (int idx=tid; idx<87; idx+=256){
    a1s[idx] = whs2[idx*2]*outa[0] + whs2[idx*2+1]*outa[1];
    a2s[idx] = whs2[idx*2]*outa[2] + whs2[idx*2+1]*outa[3];
  }
  __syncthreads();
  for (int i=0;i<22;++i){
    int n = w + 4*i;
    if (n<87){
      float a1n = a1s[n];
      float x1 = a1n + a2s[lane];
      float e1 = (adj[n*87+lane]>0.f) ? (x1>0.f?x1:0.2f*x1) : -9e15f;
      float e2 = -INFINITY;
      if (lane<23){
        float x2 = a1n + a2s[64+lane];
        e2 = (adj[n*87+64+lane]>0.f) ? (x2>0.f?x2:0.2f*x2) : -9e15f;
      }
      float mx  = warp_max(fmaxf(e1,e2));
      float ex1 = expf(e1-mx);
      float ex2 = (lane<23)?expf(e2-mx):0.f;
      float inv = 1.f/warp_sum(ex1+ex2);
      float at1 = ex1*inv, at2 = ex2*inv;
      float p0 = at1*whs2[lane*2];
      float p1 = at1*whs2[lane*2+1];
      if (lane<23){ p0 += at2*whs2[(64+lane)*2]; p1 += at2*whs2[(64+lane)*2+1]; }
      float s0 = warp_sum(p0);
      float s1 = warp_sum(p1);
      float ftv = ft_vec[(size_t)(b*87+n)*64 + lane];
      float d0 = warp_sum(ftv*lxW[lane]);
      float d1 = warp_sum(ftv*lxW[64+lane]);
      float dp = warp_sum(ftv*lpW[lane]);
      if (lane==0){
        float ep  = tanhf(dp + lpb[0])*0.01f;
        float o10 = tanhf(d0 + lxb[0]);
        float o11 = tanhf(d1 + lxb[1]);
        float g0 = (s0>0.f)?s0:expm1f(s0);
        float g1 = (s1>0.f)?s1:expm1f(s1);
        float* op = out + (size_t)(b*87+n)*3;
        op[0] = ep; op[1] = g0 + o10; op[2] = g1 + o11;
      }
    }
  }
}

// ---------------------------------------------------------------------------
extern "C" void kernel_launch(void* const* d_in, const int* in_sizes, int n_in,
                              void* d_out, int out_size, void* d_ws, size_t ws_size,
                              hipStream_t stream){
  const float* text      = (const float*)d_in[0];
  const float* price     = (const float*)d_in[1];
  const float* adj       = (const float*)d_in[2];
  const float* grup_Wih  = (const float*)d_in[4];
  const float* grup_Whh  = (const float*)d_in[5];
  const float* grup_bih  = (const float*)d_in[6];
  const float* grup_bhh  = (const float*)d_in[7];
  const float* tgru_Wih  = (const float*)d_in[8];
  const float* tgru_Whh  = (const float*)d_in[9];
  const float* tgru_bih  = (const float*)d_in[10];
  const float* tgru_bhh  = (const float*)d_in[11];
  const float* grut_Wih  = (const float*)d_in[12];
  const float* grut_Whh  = (const float*)d_in[13];
  const float* grut_bih  = (const float*)d_in[14];
  const float* grut_bhh  = (const float*)d_in[15];
  const float* attnp_W1  = (const float*)d_in[16];
  const float* attnp_b1  = (const float*)d_in[17];
  const float* attnp_W2  = (const float*)d_in[18];
  const float* attnp_b2  = (const float*)d_in[19];
  const float* attnp_V   = (const float*)d_in[20];
  const float* attnp_bV  = (const float*)d_in[21];
  const float* attw_W1   = (const float*)d_in[22];
  const float* attw_b1   = (const float*)d_in[23];
  const float* attw_W2   = (const float*)d_in[24];
  const float* attw_b2   = (const float*)d_in[25];
  const float* attw_V    = (const float*)d_in[26];
  const float* attw_bV   = (const float*)d_in[27];
  const float* attnt_W1  = (const float*)d_in[28];
  const float* attnt_b1  = (const float*)d_in[29];
  const float* attnt_W2  = (const float*)d_in[30];
  const float* attnt_b2  = (const float*)d_in[31];
  const float* attnt_V   = (const float*)d_in[32];
  const float* attnt_bV  = (const float*)d_in[33];
  const float* bil_W     = (const float*)d_in[34];
  const float* bil_b     = (const float*)d_in[35];
  const float* lx_W      = (const float*)d_in[36];
  const float* lx_b      = (const float*)d_in[37];
  const float* lp_W      = (const float*)d_in[38];
  const float* lp_b      = (const float*)d_in[39];
  const float* gat_W     = (const float*)d_in[40];
  const float* gat_a     = (const float*)d_in[41];
  const float* out_W     = (const float*)d_in[42];
  const float* out_a     = (const float*)d_in[43];

  float* ws       = (float*)d_ws;
  float* xi_t     = ws;                      // 20,044,800
  float* full_t   = xi_t   + 20044800;       //  6,681,600
  float* news     = full_t + 6681600;        //    222,720
  float* x_price  = news   + 222720;         //     44,544
  float* text_vec = x_price + 44544;         //     44,544
  float* ft_vec   = text_vec + 44544;        //     44,544
  float* Wh_g     = ft_vec + 44544;          //  2,850,816
  float* a1h      = Wh_g   + 2850816;        //      5,568
  float* a2h      = a1h    + 5568;           //      5,568
  float* xg       = a2h    + 5568;           //    356,352
  float* q        = Wh_g;                    // alias (disjoint lifetime)

  k_tweet_proj<<<dim3(3,5,87),256,0,stream>>>(text, tgru_Wih, tgru_bih, xi_t);
  k_gru30<<<435,384,0,stream>>>(xi_t, tgru_Whh, tgru_bhh, attw_W1, attw_b1, full_t, q);
  k_uproj<<<435,256,0,stream>>>(full_t, q, attw_W2, attw_b2, attw_V, attw_bV, news);
  k_stock<<<174,384,0,stream>>>(price, news,
      grup_Wih, grup_Whh, grup_bih, grup_bhh,
      attnp_W1, attnp_b1, attnp_W2, attnp_b2, attnp_V, attnp_bV,
      grut_Wih, grut_Whh, grut_bih, grut_bhh,
      attnt_W1, attnt_b1, attnt_W2, attnt_b2, attnt_V, attnt_bV,
      x_price, text_vec);
  k_bilinear<<<dim3(16,87),256,0,stream>>>(text_vec, x_price, bil_W, bil_b, ft_vec);
  k_gat_wh<<<64,256,0,stream>>>(ft_vec, gat_W, gat_a, Wh_g, a1h, a2h);
  k_gat_att<<<64,256,0,stream>>>(Wh_g, a1h, a2h, adj, xg);
  k_final<<<8,256,0,stream>>>(xg, ft_vec, out_W, out_a, lx_W, lx_b, lp_W, lp_b,
      adj, (float*)d_out);
}

// Round 5
// 769.590 us; speedup vs baseline: 1.3317x; 1.1646x over previous
//
#include <hip/hip_runtime.h>
#include <math.h>

// Model dims: S=87, B=8, D=5, T=30, H=64, G=192, K_text=512

typedef short s16x8 __attribute__((ext_vector_type(8)));
typedef float f32x4 __attribute__((ext_vector_type(4)));

__device__ __forceinline__ float sigmoidf_(float x){ return 1.0f/(1.0f+expf(-x)); }

__device__ __forceinline__ float warp_sum(float v){
  #pragma unroll
  for (int off=32; off>0; off>>=1) v += __shfl_xor(v, off, 64);
  return v;
}
__device__ __forceinline__ float warp_max(float v){
  #pragma unroll
  for (int off=32; off>0; off>>=1) v = fmaxf(v, __shfl_xor(v, off, 64));
  return v;
}

// truncation split: x ~= hi + lo with |err| ~ 2^-14 |x| (3 VALU ops/elem)
__device__ __forceinline__ void split_bf16(float x, unsigned short& hi, unsigned short& lo){
  unsigned u = __float_as_uint(x);
  hi = (unsigned short)(u >> 16);
  float r = x - __uint_as_float(u & 0xffff0000u);
  lo = (unsigned short)(__float_as_uint(r) >> 16);
}

union U8 { unsigned short u[8]; s16x8 v; };

// ---------------------------------------------------------------------------
// Kernel 1: tweet input projection via split-bf16 MFMA.
// 1-deep register prefetch (known-good: 88 VGPR, 5 waves/SIMD).
// NOTE: 2-deep ping-pong REGRESSED 144->299us (VGPR 144, occupancy cliff).
// ---------------------------------------------------------------------------
__global__ __launch_bounds__(256) void k_tweet_proj(
    const float* __restrict__ text, const float* __restrict__ Wih,
    const float* __restrict__ bih, float* __restrict__ xi_t){
  __shared__ short lds[17408];   // Ah[2560] Al[2560] Bh[6144] Bl[6144] shorts = 34816 B
  const int tid = threadIdx.x;
  const int mb = blockIdx.x, d = blockIdx.y, s = blockIdx.z;
  const int lane = tid & 63, w = tid >> 6, quad = lane >> 4;

  const float* srcp[5]; int dsth[5]; int dstl[5]; bool val[5];
  #pragma unroll
  for (int i=0;i<5;++i){
    int c = tid + i*256;
    val[i] = (c < 1088);
    int cc = val[i] ? c : 0;
    int tile = cc>>6, slot = cc&63, k8 = slot>>4, i16 = slot&15;
    if (tile < 5){
      int row = mb*80 + tile*16 + i16;           // always < 240
      int b = row/30, t = row - b*30;
      srcp[i] = text + (size_t)(b*13050 + s*150 + d*30 + t)*512 + k8*8;
      dsth[i] = tile*512 + slot*8;
      dstl[i] = dsth[i] + 2560;
    } else {
      int g = (tile-5)*16 + i16;
      srcp[i] = Wih + (size_t)(s*192+g)*512 + k8*8;
      dsth[i] = 5120 + (tile-5)*512 + slot*8;
      dstl[i] = dsth[i] + 6144;
    }
  }

  f32x4 acc[5][3] = {};

  // prologue: preload chunk 0 into registers
  float4 v0[5], v1[5];
  #pragma unroll
  for (int i=0;i<5;++i){
    if (val[i]){
      v0[i] = *(const float4*)srcp[i];
      v1[i] = *(const float4*)(srcp[i]+4);
    }
  }

  for (int kc=0; kc<16; ++kc){
    __syncthreads();   // previous chunk's LDS reads done -> safe to overwrite
    #pragma unroll
    for (int i=0;i<5;++i){
      if (val[i]){
        float xs[8] = {v0[i].x,v0[i].y,v0[i].z,v0[i].w,v1[i].x,v1[i].y,v1[i].z,v1[i].w};
        U8 hv, lv;
        #pragma unroll
        for (int j=0;j<8;++j) split_bf16(xs[j], hv.u[j], lv.u[j]);
        *(s16x8*)&lds[dsth[i]] = hv.v;
        *(s16x8*)&lds[dstl[i]] = lv.v;
        if (kc < 15){
          const float* sp = srcp[i] + (kc+1)*32;
          v0[i] = *(const float4*)sp;
          v1[i] = *(const float4*)(sp+4);
        }
      }
    }
    __syncthreads();
    s16x8 ah[5], al[5], bh[3], bl[3];
    #pragma unroll
    for (int mt=0;mt<5;++mt){
      ah[mt] = *(const s16x8*)&lds[mt*512 + lane*8];
      al[mt] = *(const s16x8*)&lds[2560 + mt*512 + lane*8];
    }
    #pragma unroll
    for (int nl=0;nl<3;++nl){
      int nt = w*3+nl;
      bh[nl] = *(const s16x8*)&lds[5120 + nt*512 + lane*8];
      bl[nl] = *(const s16x8*)&lds[11264 + nt*512 + lane*8];
    }
    #pragma unroll
    for (int mt=0;mt<5;++mt){
      #pragma unroll
      for (int nl=0;nl<3;++nl){
        acc[mt][nl] = __builtin_amdgcn_mfma_f32_16x16x32_bf16(ah[mt], bh[nl], acc[mt][nl], 0,0,0);
        acc[mt][nl] = __builtin_amdgcn_mfma_f32_16x16x32_bf16(ah[mt], bl[nl], acc[mt][nl], 0,0,0);
        acc[mt][nl] = __builtin_amdgcn_mfma_f32_16x16x32_bf16(al[mt], bh[nl], acc[mt][nl], 0,0,0);
      }
    }
  }

  // epilogue: C/D layout col=lane&15, row=quad*4+reg
  const size_t obase = (size_t)(s*5+d)*240;
  #pragma unroll
  for (int nl=0;nl<3;++nl){
    int g = (w*3+nl)*16 + (lane&15);
    float bias = bih[s*192+g];
    #pragma unroll
    for (int mt=0;mt<5;++mt){
      #pragma unroll
      for (int reg=0;reg<4;++reg){
        int row = mb*80 + mt*16 + quad*4 + reg;
        xi_t[(obase+row)*192 + g] = acc[mt][nl][reg] + bias;
      }
    }
  }
}

// ---------------------------------------------------------------------------
// Kernel 2: tweet GRU (30 steps), one block per (s,d).
// Gate GEMV via MFMA: A = Whh (t-invariant, split-bf16 fragments held in
// REGISTERS: 2 g-tiles x 2 k-chunks x hi/lo per wave), B = h (split per
// step, 16 elems/lane). 12 MFMA/step/wave replaces 512 VALU inst/thread
// (readlane version, 170us) and 80 b128 LDS reads/wave (LDS version, 144us).
// ---------------------------------------------------------------------------
__global__ __launch_bounds__(384) void k_gru30(
    const float* __restrict__ xi_t, const float* __restrict__ Whh, const float* __restrict__ bhh,
    const float* __restrict__ W1, const float* __restrict__ b1,
    float* __restrict__ full_t, float* __restrict__ q){
  __shared__ float gh[1568];   // [b][196] (stride 196 spreads banks on b128 writes)
  __shared__ float h[544];     // [b][68]
  const int tid = threadIdx.x;
  const int bid = blockIdx.x;
  const int s = bid/5;
  const int lane = tid & 63;
  const int wv   = tid >> 6;       // wave 0..5
  const int row16 = lane & 15;     // A-row (g within tile) / D-col (b)
  const int koct  = lane >> 4;     // 0..3: k-octet
  const bool bval = row16 < 8;
  const int bcol  = row16;

  // ---- static A fragments: Whh g-tiles {2wv, 2wv+1}, kc {0,1}, hi/lo ----
  s16x8 Ah[2][2], Al[2][2];
  f32x4 bias[2];
  #pragma unroll
  for (int gi=0; gi<2; ++gi){
    const int gt = 2*wv + gi;
    #pragma unroll
    for (int kc=0; kc<2; ++kc){
      const float* src = Whh + (size_t)(s*192 + gt*16 + row16)*64 + kc*32 + koct*8;
      float4 x0 = *(const float4*)src;
      float4 x1 = *(const float4*)(src+4);
      float xs[8] = {x0.x,x0.y,x0.z,x0.w,x1.x,x1.y,x1.z,x1.w};
      U8 hv, lv;
      #pragma unroll
      for (int j=0;j<8;++j) split_bf16(xs[j], hv.u[j], lv.u[j]);
      Ah[gi][kc] = hv.v; Al[gi][kc] = lv.v;
    }
    #pragma unroll
    for (int reg=0;reg<4;++reg)
      bias[gi][reg] = bhh[s*192 + gt*16 + koct*4 + reg];
  }

  for (int idx=tid; idx<544; idx+=384) h[idx] = 0.f;

  const size_t sd240 = (size_t)bid*240;
  // apply-phase ownership: item idx=tid (if<512) and idx=tid+384 (tid<128)
  float xp[2][3]; float hprev[2] = {0.f, 0.f};
  #pragma unroll
  for (int u2=0;u2<2;++u2){
    int idx = tid + u2*384;
    if (idx < 512){
      int bb = idx>>6, j = idx&63;
      const float* xr = xi_t + (sd240 + bb*30 + 0)*192 + j;
      xp[u2][0]=xr[0]; xp[u2][1]=xr[64]; xp[u2][2]=xr[128];
    }
  }
  __syncthreads();

  for (int t=0; t<30; ++t){
    // ---- B fragments from h: col=b (lanes 0..7 of each 16), k=kc*32+koct*8+j ----
    s16x8 Bh[2], Bl[2];
    #pragma unroll
    for (int kc=0;kc<2;++kc){
      float4 x0 = {0.f,0.f,0.f,0.f}, x1 = {0.f,0.f,0.f,0.f};
      if (bval){
        const float* hp = &h[bcol*68 + kc*32 + koct*8];
        x0 = *(const float4*)hp;
        x1 = *(const float4*)(hp+4);
      }
      float xs[8] = {x0.x,x0.y,x0.z,x0.w,x1.x,x1.y,x1.z,x1.w};
      U8 hv, lv;
      #pragma unroll
      for (int j=0;j<8;++j) split_bf16(xs[j], hv.u[j], lv.u[j]);
      Bh[kc] = hv.v; Bl[kc] = lv.v;
    }
    // ---- 12 MFMA: acc[gi] = bias + Whh_tile x h (3-product split) ----
    f32x4 acc0 = bias[0], acc1 = bias[1];
    #pragma unroll
    for (int kc=0;kc<2;++kc){
      acc0 = __builtin_amdgcn_mfma_f32_16x16x32_bf16(Ah[0][kc], Bh[kc], acc0, 0,0,0);
      acc1 = __builtin_amdgcn_mfma_f32_16x16x32_bf16(Ah[1][kc], Bh[kc], acc1, 0,0,0);
      acc0 = __builtin_amdgcn_mfma_f32_16x16x32_bf16(Ah[0][kc], Bl[kc], acc0, 0,0,0);
      acc1 = __builtin_amdgcn_mfma_f32_16x16x32_bf16(Ah[1][kc], Bl[kc], acc1, 0,0,0);
      acc0 = __builtin_amdgcn_mfma_f32_16x16x32_bf16(Al[0][kc], Bh[kc], acc0, 0,0,0);
      acc1 = __builtin_amdgcn_mfma_f32_16x16x32_bf16(Al[1][kc], Bh[kc], acc1, 0,0,0);
    }
    // D layout: col=lane&15 (=b), row=koct*4+reg (=g within tile)
    if (bval){
      *(f32x4*)&gh[bcol*196 + (2*wv+0)*16 + koct*4] = acc0;
      *(f32x4*)&gh[bcol*196 + (2*wv+1)*16 + koct*4] = acc1;
    }
    __syncthreads();

    // ---- gate apply ----
    float cur[2][3];
    #pragma unroll
    for (int u2=0;u2<2;++u2){ cur[u2][0]=xp[u2][0]; cur[u2][1]=xp[u2][1]; cur[u2][2]=xp[u2][2]; }
    if (t < 29){
      #pragma unroll
      for (int u2=0;u2<2;++u2){
        int idx = tid + u2*384;
        if (idx < 512){
          int bb = idx>>6, j = idx&63;
          const float* xr = xi_t + (sd240 + bb*30 + t + 1)*192 + j;
          xp[u2][0]=xr[0]; xp[u2][1]=xr[64]; xp[u2][2]=xr[128];
        }
      }
    }
    #pragma unroll
    for (int u2=0;u2<2;++u2){
      int idx = tid + u2*384;
      if (idx < 512){
        int bb = idx>>6, j = idx&63;
        float r = sigmoidf_(cur[u2][0] + gh[bb*196+j]);
        float z = sigmoidf_(cur[u2][1] + gh[bb*196+64+j]);
        float n = tanhf(   cur[u2][2] + r*gh[bb*196+128+j]);
        float hn = (1.f - z)*n + z*hprev[u2];
        hprev[u2] = hn;
        h[bb*68+j] = hn;
        full_t[(sd240 + bb*30 + t)*64 + j] = hn;
      }
    }
    __syncthreads();
  }

  // q = W1 h_last + b1
  for (int idx=tid; idx<512; idx+=384){
    int bb = idx>>6, j = idx&63;
    float acc = b1[s*64+j];
    const float* wr = W1 + (size_t)(s*64+j)*64;
    #pragma unroll
    for (int kq=0;kq<16;++kq){
      float4 w4 = *(const float4*)(wr+kq*4);
      acc += h[bb*68+kq*4+0]*w4.x + h[bb*68+kq*4+1]*w4.y
           + h[bb*68+kq*4+2]*w4.z + h[bb*68+kq*4+3]*w4.w;
    }
    q[(size_t)bid*512 + idx] = acc;
  }
}

// ---------------------------------------------------------------------------
// Kernel 3: attention projection u = full_t @ W2^T via split-bf16 MFMA, fused
// with score=V.tanh(q+u+b2)+bV, softmax over T, weighted sum -> news.
// ---------------------------------------------------------------------------
__global__ __launch_bounds__(256) void k_uproj(
    const float* __restrict__ full_t, const float* __restrict__ q,
    const float* __restrict__ W2, const float* __restrict__ b2,
    const float* __restrict__ V, const float* __restrict__ bV,
    float* __restrict__ news){
  __shared__ short lds[19456];   // Ah[7680] Al[7680] Bh[2048] Bl[2048] = 38912 B
  float* scpart = (float*)&lds[15360];
  float* ssc = scpart + 960;
  float* swt = ssc + 240;
  const int tid = threadIdx.x, lane = tid&63, w = tid>>6, quad = lane>>4;
  const int bid = blockIdx.x;
  const int s = bid/5;
  const size_t sd240 = (size_t)bid*240;

  const float* srcp2[5]; int dh2[5]; int ldo2[5]; bool val2[5];
  #pragma unroll
  for (int i=0;i<5;++i){
    int idx = tid + i*256;
    val2[i] = (idx < 1216);
    int ix = val2[i] ? idx : 0;
    if (ix < 960){
      int r = ix>>2, kc8 = ix&3;
      srcp2[i] = full_t + (sd240 + r)*64 + kc8*8;
      dh2[i] = ((r>>4)*64 + ((r&15)|(kc8<<4)))*8; ldo2[i] = 7680;
    } else {
      int c = ix - 960; int j = c>>2, kc8 = c&3;
      srcp2[i] = W2 + (size_t)(s*64+j)*64 + kc8*8;
      dh2[i] = 15360 + ((j>>4)*64 + ((j&15)|(kc8<<4)))*8; ldo2[i] = 2048;
    }
  }

  float4 w0r[5], w1r[5];
  #pragma unroll
  for (int i=0;i<5;++i){
    if (val2[i]){
      w0r[i] = *(const float4*)srcp2[i];
      w1r[i] = *(const float4*)(srcp2[i]+4);
    }
  }

  f32x4 acc[15] = {};
  for (int kc=0; kc<2; ++kc){
    __syncthreads();
    #pragma unroll
    for (int i=0;i<5;++i){
      if (val2[i]){
        float xs[8] = {w0r[i].x,w0r[i].y,w0r[i].z,w0r[i].w,w1r[i].x,w1r[i].y,w1r[i].z,w1r[i].w};
        U8 hv, lv;
        #pragma unroll
        for (int j2=0;j2<8;++j2) split_bf16(xs[j2], hv.u[j2], lv.u[j2]);
        *(s16x8*)&lds[dh2[i]] = hv.v;
        *(s16x8*)&lds[dh2[i]+ldo2[i]] = lv.v;
        if (kc == 0){
          const float* sp = srcp2[i] + 32;
          w0r[i] = *(const float4*)sp;
          w1r[i] = *(const float4*)(sp+4);
        }
      }
    }
    __syncthreads();
    s16x8 bh = *(const s16x8*)&lds[15360 + (w*64+lane)*8];
    s16x8 bl = *(const s16x8*)&lds[17408 + (w*64+lane)*8];
    #pragma unroll
    for (int mt=0;mt<15;++mt){
      s16x8 ah = *(const s16x8*)&lds[(mt*64+lane)*8];
      s16x8 al = *(const s16x8*)&lds[7680+(mt*64+lane)*8];
      acc[mt] = __builtin_amdgcn_mfma_f32_16x16x32_bf16(ah, bh, acc[mt], 0,0,0);
      acc[mt] = __builtin_amdgcn_mfma_f32_16x16x32_bf16(ah, bl, acc[mt], 0,0,0);
      acc[mt] = __builtin_amdgcn_mfma_f32_16x16x32_bf16(al, bh, acc[mt], 0,0,0);
    }
  }
  __syncthreads();

  {
    int j = w*16 + (lane&15);
    float Vj = V[s*64+j], b2j = b2[s*64+j];
    const float* qb = q + (size_t)bid*512;
    #pragma unroll
    for (int mt=0;mt<15;++mt){
      #pragma unroll
      for (int reg=0;reg<4;++reg){
        int row = mt*16 + quad*4 + reg;
        int bb = row/30;
        float val = tanhf(acc[mt][reg] + b2j + qb[bb*64+j]) * Vj;
        val += __shfl_xor(val, 1, 64);
        val += __shfl_xor(val, 2, 64);
        val += __shfl_xor(val, 4, 64);
        val += __shfl_xor(val, 8, 64);
        if ((lane&15)==0) scpart[w*240 + row] = val;
      }
    }
  }
  __syncthreads();
  float bVs = bV[s];
  for (int idx=tid; idx<240; idx+=256)
    ssc[idx] = scpart[idx] + scpart[240+idx] + scpart[480+idx] + scpart[720+idx] + bVs;
  __syncthreads();
  if (tid < 8){
    float mx = -1e30f;
    for (int t=0;t<30;++t) mx = fmaxf(mx, ssc[tid*30+t]);
    float ssum = 0.f;
    for (int t=0;t<30;++t){ float e = expf(ssc[tid*30+t]-mx); swt[tid*30+t] = e; ssum += e; }
    float inv = 1.f/ssum;
    for (int t=0;t<30;++t) swt[tid*30+t] *= inv;
  }
  __syncthreads();
  for (int idx=tid; idx<512; idx+=256){
    int bb = idx>>6, jj = idx&63;
    float a = 0.f;
    for (int t=0;t<30;++t) a += swt[bb*30+t]*full_t[(sd240 + bb*30 + t)*64 + jj];
    news[(size_t)bid*512 + idx] = a;
  }
}

// ---------------------------------------------------------------------------
// Fused stock kernel: replaces k_price (blocks 0..86) and k_day (87..173).
// ---------------------------------------------------------------------------
__global__ __launch_bounds__(384) void k_stock(
    const float* __restrict__ price, const float* __restrict__ news,
    const float* __restrict__ pWih, const float* __restrict__ pWhh,
    const float* __restrict__ pbih, const float* __restrict__ pbhh,
    const float* __restrict__ pW1, const float* __restrict__ pb1,
    const float* __restrict__ pW2, const float* __restrict__ pb2,
    const float* __restrict__ pV, const float* __restrict__ pbV,
    const float* __restrict__ dWih, const float* __restrict__ dWhh,
    const float* __restrict__ dbih, const float* __restrict__ dbhh,
    const float* __restrict__ dW1, const float* __restrict__ db1,
    const float* __restrict__ dW2, const float* __restrict__ db2,
    const float* __restrict__ dV, const float* __restrict__ dbV,
    float* __restrict__ x_price, float* __restrict__ text_vec){
  __shared__ float sm[27904];          // 111.6 KB
  float* Wt  = sm;            // 12288: transposed Wih, then Whh, then W2t reuse
  float* xi  = sm + 12288;    // 7680
  float* full= sm + 19968;    // 2560
  float* h   = sm + 22528;    // 544 (8 x 68)
  float* gh  = sm + 23072;    // 1568 (8 x 196); tail reuse: Vs/b2s/sc/wsm
  float* nw  = sm + 24640;    // 2560
  float* bihs= sm + 27200;    // 192
  float* qq  = sm + 27392;    // 512

  const int tid = threadIdx.x;
  const int bid = blockIdx.x;
  const bool isday = (bid >= 87);
  const int s = isday ? (bid - 87) : bid;

  const float* Wih = isday ? dWih : pWih;
  const float* Whh = isday ? dWhh : pWhh;
  const float* bih = isday ? dbih : pbih;
  const float* bhh = isday ? dbhh : pbhh;
  const float* W1  = isday ? dW1  : pW1;
  const float* b1  = isday ? db1  : pb1;
  const float* W2  = isday ? dW2  : pW2;
  const float* b2  = isday ? db2  : pb2;
  const float* V   = isday ? dV   : pV;
  const float* bV  = isday ? dbV  : pbV;

  // ---- phase A: stage inputs, zero h, stage bih, stage Wih (transposed) ----
  if (isday){
    for (int idx=tid; idx<2560; idx+=384) nw[idx] = news[(size_t)s*2560 + idx];
    for (int idx=tid; idx<3072; idx+=384){
      int g = idx>>4, kq = idx&15;
      float4 wv = *(const float4*)&Wih[(size_t)(s*192+g)*64 + kq*4];
      Wt[(kq*4+0)*192+g]=wv.x; Wt[(kq*4+1)*192+g]=wv.y;
      Wt[(kq*4+2)*192+g]=wv.z; Wt[(kq*4+3)*192+g]=wv.w;
    }
  } else {
    for (int idx=tid; idx<120; idx+=384){
      int bb = idx/15, rem = idx - bb*15; int dd = rem/3, k = rem - dd*3;
      nw[idx] = price[(size_t)((bb*87+s)*5+dd)*3 + k];
    }
    for (int idx=tid; idx<576; idx+=384) Wt[idx] = Wih[(size_t)s*576 + idx]; // [g][3]
  }
  for (int idx=tid; idx<544; idx+=384) h[idx] = 0.f;
  for (int idx=tid; idx<192; idx+=384) bihs[idx] = bih[s*192+idx];
  __syncthreads();

  // ---- phase B: xi[bd*192+g] from LDS only ----
  if (isday){
    for (int idx=tid; idx<7680; idx+=384){
      int bd = idx/192, g = idx - bd*192;
      int bb = bd/5, dd = bd - bb*5;
      const float* xr = nw + (dd*8+bb)*64;
      float a0=0.f,a1=0.f,a2=0.f,a3=0.f;
      #pragma unroll
      for (int k=0;k<64;k+=4){
        a0 += xr[k]  *Wt[(k  )*192+g];
        a1 += xr[k+1]*Wt[(k+1)*192+g];
        a2 += xr[k+2]*Wt[(k+2)*192+g];
        a3 += xr[k+3]*Wt[(k+3)*192+g];
      }
      xi[idx] = bihs[g] + ((a0+a1)+(a2+a3));
    }
  } else {
    for (int idx=tid; idx<7680; idx+=384){
      int bd = idx/192, g = idx - bd*192;
      xi[idx] = bihs[g] + nw[bd*3]*Wt[g*3] + nw[bd*3+1]*Wt[g*3+1] + nw[bd*3+2]*Wt[g*3+2];
    }
  }
  __syncthreads();

  // ---- phase C: stage Whh transposed (overwrite Wt) ----
  for (int idx=tid; idx<3072; idx+=384){
    int g = idx>>4, kq = idx&15;
    float4 wv = *(const float4*)&Whh[(size_t)(s*192+g)*64 + kq*4];
    Wt[(kq*4+0)*192+g]=wv.x; Wt[(kq*4+1)*192+g]=wv.y;
    Wt[(kq*4+2)*192+g]=wv.z; Wt[(kq*4+3)*192+g]=wv.w;
  }
  const int gq = tid>>3, b = tid&7;        // gq 0..47, b 0..7
  float4 bh4 = *(const float4*)&bhh[s*192 + gq*4];
  __syncthreads();

  // ---- phase D: 5 GRU steps ----
  for (int dd=0; dd<5; ++dd){
    float4 acc = bh4;
    #pragma unroll
    for (int kq=0;kq<16;++kq){
      float4 h4 = *(const float4*)&h[b*68+kq*4];
      float4 w0 = *(const float4*)&Wt[(kq*4+0)*192+gq*4];
      float4 w1 = *(const float4*)&Wt[(kq*4+1)*192+gq*4];
      float4 w2 = *(const float4*)&Wt[(kq*4+2)*192+gq*4];
      float4 w3 = *(const float4*)&Wt[(kq*4+3)*192+gq*4];
      acc.x += h4.x*w0.x + h4.y*w1.x + h4.z*w2.x + h4.w*w3.x;
      acc.y += h4.x*w0.y + h4.y*w1.y + h4.z*w2.y + h4.w*w3.y;
      acc.z += h4.x*w0.z + h4.y*w1.z + h4.z*w2.z + h4.w*w3.z;
      acc.w += h4.x*w0.w + h4.y*w1.w + h4.z*w2.w + h4.w*w3.w;
    }
    *(float4*)&gh[b*196+gq*4] = acc;
    __syncthreads();
    for (int idx=tid; idx<512; idx+=384){
      int bb = idx>>6, j = idx&63;
      const float* xr = xi + (bb*5+dd)*192;
      float r = sigmoidf_(xr[j]     + gh[bb*196+j]);
      float z = sigmoidf_(xr[64+j]  + gh[bb*196+64+j]);
      float n = tanhf(   xr[128+j] + r*gh[bb*196+128+j]);
      float hv = h[bb*68+j];
      float hn = (1.f-z)*n + z*hv;
      h[bb*68+j] = hn;
      full[(bb*5+dd)*64 + j] = hn;
    }
    __syncthreads();
  }

  // ---- phase E: Bahdanau attention over D=5 ----
  float* W2t = Wt;                 // 4096, gates done
  float* Vs  = gh;                 // 64
  float* b2s = gh + 64;            // 64
  float* sc  = gh + 128;           // 40
  float* wsm = gh + 168;           // 40
  for (int idx=tid; idx<512; idx+=384){
    int bb = idx>>6, j = idx&63;
    float a0=0.f,a1=0.f,a2=0.f,a3=0.f;
    float accq = b1[s*64+j];
    const float* wr = W1 + (size_t)(s*64+j)*64;
    #pragma unroll
    for (int kq=0;kq<16;++kq){
      float4 w4 = *(const float4*)(wr+kq*4);
      a0 += h[bb*68+kq*4+0]*w4.x; a1 += h[bb*68+kq*4+1]*w4.y;
      a2 += h[bb*68+kq*4+2]*w4.z; a3 += h[bb*68+kq*4+3]*w4.w;
    }
    qq[idx] = accq + ((a0+a1)+(a2+a3));
  }
  for (int idx=tid; idx<1024; idx+=384){
    int j = idx>>4, kq = idx&15;
    float4 w4 = *(const float4*)&W2[(size_t)(s*64+j)*64 + kq*4];
    W2t[(kq*4+0)*64+j]=w4.x; W2t[(kq*4+1)*64+j]=w4.y;
    W2t[(kq*4+2)*64+j]=w4.z; W2t[(kq*4+3)*64+j]=w4.w;
  }
  for (int idx=tid; idx<64; idx+=384){ Vs[idx]=V[s*64+idx]; b2s[idx]=b2[s*64+idx]; }
  __syncthreads();
  const int w = tid>>6, lane = tid&63;
  const float bVs = bV[s];
  for (int pair=w; pair<40; pair+=6){
    int bb = pair/5, dd = pair - bb*5;
    const float* fr = full + (bb*5+dd)*64;
    float u0=0.f,u1=0.f,u2=0.f,u3=0.f;
    #pragma unroll
    for (int k=0;k<64;k+=4){
      u0 += W2t[(k  )*64+lane]*fr[k];
      u1 += W2t[(k+1)*64+lane]*fr[k+1];
      u2 += W2t[(k+2)*64+lane]*fr[k+2];
      u3 += W2t[(k+3)*64+lane]*fr[k+3];
    }
    float u = qq[bb*64+lane] + b2s[lane] + ((u0+u1)+(u2+u3));
    float p = warp_sum(tanhf(u)*Vs[lane]);
    if (lane==0) sc[pair] = p + bVs;
  }
  __syncthreads();
  if (tid<8){
    float mx=-1e30f; for (int dd=0;dd<5;++dd) mx=fmaxf(mx, sc[tid*5+dd]);
    float ssum=0.f;
    for (int dd=0;dd<5;++dd){ float e=expf(sc[tid*5+dd]-mx); wsm[tid*5+dd]=e; ssum+=e; }
    float inv=1.f/ssum;
    for (int dd=0;dd<5;++dd) wsm[tid*5+dd]*=inv;
  }
  __syncthreads();
  float* outv = isday ? text_vec : x_price;
  for (int idx=tid; idx<512; idx+=384){
    int bb=idx>>6, j=idx&63;
    float acc=0.f;
    for (int dd=0;dd<5;++dd) acc += wsm[bb*5+dd]*full[(bb*5+dd)*64+j];
    outv[(size_t)(s*8+bb)*64 + j] = acc;
  }
}

// ---------------------------------------------------------------------------
__global__ __launch_bounds__(256) void k_bilinear(
    const float* __restrict__ text_vec, const float* __restrict__ x_price,
    const float* __restrict__ bilW, const float* __restrict__ bilb,
    float* __restrict__ ft_vec){
  __shared__ float tv[512], pv[512];
  const int tid = threadIdx.x;
  const int kb = blockIdx.x, s = blockIdx.y;
  for (int idx=tid; idx<512; idx+=256){ tv[idx]=text_vec[s*512+idx]; pv[idx]=x_price[s*512+idx]; }
  __syncthreads();
  const int w = tid>>6, lane = tid&63;
  const int j = (lane&15)*4;
  const int ib = lane>>4;
  float4 pj[8];
  #pragma unroll
  for (int bb=0;bb<8;++bb) pj[bb] = *(const float4*)&pv[bb*64+j];
  const int k = kb*4 + w;
  const float* base = bilW + (size_t)(s*64+k)*4096;
  float acc[8] = {0,0,0,0,0,0,0,0};
  for (int it=0; it<16; ++it){
    float4 wv = *(const float4*)(base + it*256 + lane*4);
    int i = it*4 + ib;
    #pragma unroll
    for (int bb=0;bb<8;++bb){
      float partial = wv.x*pj[bb].x + wv.y*pj[bb].y + wv.z*pj[bb].z + wv.w*pj[bb].w;
      acc[bb] += partial * tv[bb*64+i];
    }
  }
  #pragma unroll
  for (int bb=0;bb<8;++bb){
    float tot = warp_sum(acc[bb]);
    if (lane==0) ft_vec[(size_t)(bb*87+s)*64 + k] = tanhf(tot + bilb[s*64+k]);
  }
}

// ---------------------------------------------------------------------------
__global__ __launch_bounds__(256) void k_gat_wh(
    const float* __restrict__ ft_vec, const float* __restrict__ gatW,
    const float* __restrict__ gata,
    float* __restrict__ Wh_g, float* __restrict__ a1h, float* __restrict__ a2h){
  __shared__ float ftb[5568];
  __shared__ float Ws[4096];
  const int tid = threadIdx.x;
  const int hd = blockIdx.x>>3, b = blockIdx.x&7;
  for (int idx=tid; idx<5568; idx+=256) ftb[idx] = ft_vec[(size_t)b*5568 + idx];
  for (int idx=tid; idx<4096; idx+=256) Ws[idx]  = gatW[(size_t)hd*4096 + idx];
  __syncthreads();
  const int f = tid&63, sq = tid>>6;
  const float af1 = gata[hd*128 + f], af2 = gata[hd*128 + 64 + f];
  for (int p=0;p<22;++p){
    int ss = p*4 + sq;
    if (ss < 87){
      float acc = 0.f;
      #pragma unroll 16
      for (int k=0;k<64;++k) acc += ftb[ss*64+k]*Ws[k*64+f];
      Wh_g[(size_t)((hd*8+b)*87 + ss)*64 + f] = acc;
      float p1 = warp_sum(acc*af1);
      float p2 = warp_sum(acc*af2);
      if (f==0){ a1h[(hd*8+b)*87 + ss] = p1; a2h[(hd*8+b)*87 + ss] = p2; }
    }
  }
}

__global__ __launch_bounds__(256) void k_gat_att(
    const float* __restrict__ Wh_g, const float* __restrict__ a1h,
    const float* __restrict__ a2h, const float* __restrict__ adj,
    float* __restrict__ xg){
  __shared__ float whs[5568];
  __shared__ float a1s[96], a2s[96];
  __shared__ float adjs[7569];
  __shared__ float attw[4*128];
  const int tid = threadIdx.x;
  const int hd = blockIdx.x>>3, b = blockIdx.x&7;
  const int hb = hd*8+b;
  for (int idx=tid; idx<5568; idx+=256) whs[idx] = Wh_g[(size_t)hb*5568 + idx];
  for (int idx=tid; idx<87;   idx+=256){ a1s[idx]=a1h[hb*87+idx]; a2s[idx]=a2h[hb*87+idx]; }
  for (int idx=tid; idx<7569; idx+=256) adjs[idx]=adj[idx];
  __syncthreads();
  const int w = tid>>6, lane = tid&63;
  for (int i=0;i<22;++i){
    int n = w + 4*i;
    if (n < 87){
      float a1n = a1s[n];
      float x1 = a1n + a2s[lane];
      float e1 = (adjs[n*87+lane] > 0.f) ? (x1>0.f? x1 : 0.2f*x1) : -9e15f;
      float e2 = -INFINITY;
      if (lane < 23){
        float x2 = a1n + a2s[64+lane];
        e2 = (adjs[n*87+64+lane] > 0.f) ? (x2>0.f? x2 : 0.2f*x2) : -9e15f;
      }
      float mx  = warp_max(fmaxf(e1,e2));
      float ex1 = expf(e1-mx);
      float ex2 = (lane<23) ? expf(e2-mx) : 0.f;
      float inv = 1.f/warp_sum(ex1+ex2);
      attw[w*128+lane] = ex1*inv;
      if (lane<23) attw[w*128+64+lane] = ex2*inv;
      float o = 0.f;
      for (int m=0;m<87;++m) o += attw[w*128+m]*whs[m*64+lane];
      float val = (o>0.f) ? o : expm1f(o);
      xg[(size_t)(b*87+n)*512 + hd*64 + lane] = val;
    }
  }
}

// ---------------------------------------------------------------------------
__global__ __launch_bounds__(256) void k_final(
    const float* __restrict__ xg, const float* __restrict__ ft_vec,
    const float* __restrict__ outW, const float* __restrict__ outa,
    const float* __restrict__ lxW, const float* __restrict__ lxb,
    const float* __restrict__ lpW, const float* __restrict__ lpb,
    const float* __restrict__ adj, float* __restrict__ out){
  __shared__ float whs2[176];
  __shared__ float a1s[96], a2s[96];
  const int tid = threadIdx.x;
  const int b = blockIdx.x;
  const int w = tid>>6, lane = tid&63;
  for (int item=w; item<174; item+=4){
    int ss = item>>1, c = item&1;
    const float* xr = xg + (size_t)(b*87+ss)*512;
    float a = 0.f;
    #pragma unroll
    for (int kk=0;kk<8;++kk) a += xr[kk*64+lane]*outW[(kk*64+lane)*2+c];
    a = warp_sum(a);
    if (lane==0) whs2[item] = a;
  }
  __syncthreads();
  for (int idx=tid; idx<87; idx+=256){
    a1s[idx] = whs2[idx*2]*outa[0] + whs2[idx*2+1]*outa[1];
    a2s[idx] = whs2[idx*2]*outa[2] + whs2[idx*2+1]*outa[3];
  }
  __syncthreads();
  for (int i=0;i<22;++i){
    int n = w + 4*i;
    if (n<87){
      float a1n = a1s[n];
      float x1 = a1n + a2s[lane];
      float e1 = (adj[n*87+lane]>0.f) ? (x1>0.f?x1:0.2f*x1) : -9e15f;
      float e2 = -INFINITY;
      if (lane<23){
        float x2 = a1n + a2s[64+lane];
        e2 = (adj[n*87+64+lane]>0.f) ? (x2>0.f?x2:0.2f*x2) : -9e15f;
      }
      float mx  = warp_max(fmaxf(e1,e2));
      float ex1 = expf(e1-mx);
      float ex2 = (lane<23)?expf(e2-mx):0.f;
      float inv = 1.f/warp_sum(ex1+ex2);
      float at1 = ex1*inv, at2 = ex2*inv;
      float p0 = at1*whs2[lane*2];
      float p1 = at1*whs2[lane*2+1];
      if (lane<23){ p0 += at2*whs2[(64+lane)*2]; p1 += at2*whs2[(64+lane)*2+1]; }
      float s0 = warp_sum(p0);
      float s1 = warp_sum(p1);
      float ftv = ft_vec[(size_t)(b*87+n)*64 + lane];
      float d0 = warp_sum(ftv*lxW[lane]);
      float d1 = warp_sum(ftv*lxW[64+lane]);
      float dp = warp_sum(ftv*lpW[lane]);
      if (lane==0){
        float ep  = tanhf(dp + lpb[0])*0.01f;
        float o10 = tanhf(d0 + lxb[0]);
        float o11 = tanhf(d1 + lxb[1]);
        float g0 = (s0>0.f)?s0:expm1f(s0);
        float g1 = (s1>0.f)?s1:expm1f(s1);
        float* op = out + (size_t)(b*87+n)*3;
        op[0] = ep; op[1] = g0 + o10; op[2] = g1 + o11;
      }
    }
  }
}

// ---------------------------------------------------------------------------
extern "C" void kernel_launch(void* const* d_in, const int* in_sizes, int n_in,
                              void* d_out, int out_size, void* d_ws, size_t ws_size,
                              hipStream_t stream){
  const float* text      = (const float*)d_in[0];
  const float* price     = (const float*)d_in[1];
  const float* adj       = (const float*)d_in[2];
  const float* grup_Wih  = (const float*)d_in[4];
  const float* grup_Whh  = (const float*)d_in[5];
  const float* grup_bih  = (const float*)d_in[6];
  const float* grup_bhh  = (const float*)d_in[7];
  const float* tgru_Wih  = (const float*)d_in[8];
  const float* tgru_Whh  = (const float*)d_in[9];
  const float* tgru_bih  = (const float*)d_in[10];
  const float* tgru_bhh  = (const float*)d_in[11];
  const float* grut_Wih  = (const float*)d_in[12];
  const float* grut_Whh  = (const float*)d_in[13];
  const float* grut_bih  = (const float*)d_in[14];
  const float* grut_bhh  = (const float*)d_in[15];
  const float* attnp_W1  = (const float*)d_in[16];
  const float* attnp_b1  = (const float*)d_in[17];
  const float* attnp_W2  = (const float*)d_in[18];
  const float* attnp_b2  = (const float*)d_in[19];
  const float* attnp_V   = (const float*)d_in[20];
  const float* attnp_bV  = (const float*)d_in[21];
  const float* attw_W1   = (const float*)d_in[22];
  const float* attw_b1   = (const float*)d_in[23];
  const float* attw_W2   = (const float*)d_in[24];
  const float* attw_b2   = (const float*)d_in[25];
  const float* attw_V    = (const float*)d_in[26];
  const float* attw_bV   = (const float*)d_in[27];
  const float* attnt_W1  = (const float*)d_in[28];
  const float* attnt_b1  = (const float*)d_in[29];
  const float* attnt_W2  = (const float*)d_in[30];
  const float* attnt_b2  = (const float*)d_in[31];
  const float* attnt_V   = (const float*)d_in[32];
  const float* attnt_bV  = (const float*)d_in[33];
  const float* bil_W     = (const float*)d_in[34];
  const float* bil_b     = (const float*)d_in[35];
  const float* lx_W      = (const float*)d_in[36];
  const float* lx_b      = (const float*)d_in[37];
  const float* lp_W      = (const float*)d_in[38];
  const float* lp_b      = (const float*)d_in[39];
  const float* gat_W     = (const float*)d_in[40];
  const float* gat_a     = (const float*)d_in[41];
  const float* out_W     = (const float*)d_in[42];
  const float* out_a     = (const float*)d_in[43];

  float* ws       = (float*)d_ws;
  float* xi_t     = ws;                      // 20,044,800
  float* full_t   = xi_t   + 20044800;       //  6,681,600
  float* news     = full_t + 6681600;        //    222,720
  float* x_price  = news   + 222720;         //     44,544
  float* text_vec = x_price + 44544;         //     44,544
  float* ft_vec   = text_vec + 44544;        //     44,544
  float* Wh_g     = ft_vec + 44544;          //  2,850,816
  float* a1h      = Wh_g   + 2850816;        //      5,568
  float* a2h      = a1h    + 5568;           //      5,568
  float* xg       = a2h    + 5568;           //    356,352
  float* q        = Wh_g;                    // alias (disjoint lifetime)

  k_tweet_proj<<<dim3(3,5,87),256,0,stream>>>(text, tgru_Wih, tgru_bih, xi_t);
  k_gru30<<<435,384,0,stream>>>(xi_t, tgru_Whh, tgru_bhh, attw_W1, attw_b1, full_t, q);
  k_uproj<<<435,256,0,stream>>>(full_t, q, attw_W2, attw_b2, attw_V, attw_bV, news);
  k_stock<<<174,384,0,stream>>>(price, news,
      grup_Wih, grup_Whh, grup_bih, grup_bhh,
      attnp_W1, attnp_b1, attnp_W2, attnp_b2, attnp_V, attnp_bV,
      grut_Wih, grut_Whh, grut_bih, grut_bhh,
      attnt_W1, attnt_b1, attnt_W2, attnt_b2, attnt_V, attnt_bV,
      x_price, text_vec);
  k_bilinear<<<dim3(16,87),256,0,stream>>>(text_vec, x_price, bil_W, bil_b, ft_vec);
  k_gat_wh<<<64,256,0,stream>>>(ft_vec, gat_W, gat_a, Wh_g, a1h, a2h);
  k_gat_att<<<64,256,0,stream>>>(Wh_g, a1h, a2h, adj, xg);
  k_final<<<8,256,0,stream>>>(xg, ft_vec, out_W, out_a, lx_W, lx_b, lp_W, lp_b,
      adj, (float*)d_out);
}